// Round 3
// baseline (1689.995 us; speedup 1.0000x reference)
//
#include <hip/hip_runtime.h>
#include <hip/hip_bf16.h>
#include <hip/hip_fp16.h>
#include <cstdint>
#include <cstddef>

#define NN 4096
#define WPR 64   // 64-bit words per adjacency row
#define NBLK 512 // persistent grid: 2 blocks/CU on 256 CUs, co-resident by construction

typedef __attribute__((ext_vector_type(8))) unsigned short ushort8v;
typedef __attribute__((ext_vector_type(4))) unsigned short ushort4v;
typedef __attribute__((ext_vector_type(8))) short short8;
typedef __attribute__((ext_vector_type(4))) float float4v;

#define C1 30.0f
#define C2 0.3f    // 0.01 * C1

static __device__ __forceinline__ unsigned short f2bf(float x) {
    union { float f; unsigned int u; } v; v.f = x;
    unsigned int r = v.u + 0x7FFFu + ((v.u >> 16) & 1u);
    return (unsigned short)(r >> 16);
}

static __device__ __forceinline__ short8 as_s8(ushort8v v) {
    union { ushort8v u; short8 s; } x; x.u = v; return x.s;
}

// async 16B/lane global -> LDS DMA (wave-uniform LDS base + lane*16)
static __device__ __forceinline__ void gl_lds16(const unsigned short* g, unsigned short* l) {
    __builtin_amdgcn_global_load_lds(
        (const __attribute__((address_space(1))) unsigned int*)g,
        (__attribute__((address_space(3))) unsigned int*)l,
        16, 0, 0);
}

// grid-wide barrier: one single-use counter per sync point (zeroed by host memset
// each launch). Device-scope release (threadfence) -> arrive -> leader spins ->
// block barrier -> device-scope acquire (threadfence).
static __device__ __forceinline__ void gsync(unsigned* bar) {
    __syncthreads();
    __threadfence();
    if (threadIdx.x == 0) {
        __hip_atomic_fetch_add(bar, 1u, __ATOMIC_ACQ_REL, __HIP_MEMORY_SCOPE_AGENT);
        while (__hip_atomic_load(bar, __ATOMIC_ACQUIRE, __HIP_MEMORY_SCOPE_AGENT) < NBLK)
            __builtin_amdgcn_s_sleep(1);
    }
    __syncthreads();
    __threadfence();
}

// ============================ the whole GAT in one dispatch ============================
// Phases (10 grid syncs):
//  P0 : proj0 (h1 = input @ W0, inline fp32->bf16) + adj-pack + W2/W3 cvt + f1f2 zero
//  P1 : proj1 (Whbt/f1f2_0 = h1 @ W1, inline W1 cvt)
//  per layer L=0..2:  [L>0: frp]  -> rc -> att
//  tail: rout
__global__ __launch_bounds__(256, 2) void mega(
    const float* __restrict__ input, const int* __restrict__ adj,
    const float* __restrict__ W0, const float* __restrict__ W1,
    const float* __restrict__ a1v, const float* __restrict__ W2,
    const float* __restrict__ a2v, const float* __restrict__ W3,
    const float* __restrict__ a3v, float* __restrict__ out,
    unsigned long long* bits, unsigned short* h1, unsigned short* Whbt,
    unsigned short* Wbt, float* f1f2, float4* rowco, float2* tab2,
    unsigned short* parth, unsigned* bars)
{
    const int bid = blockIdx.x;
    const int t = threadIdx.x;
    const int lane = t & 63, wave = t >> 6;
    const int g = lane >> 4, ml = lane & 15;
    __shared__ __align__(16) char smem[50688];   // max over phases (proj: 50688)

    //================= P0 =================
    {
        // zero f1f2 (3 layers x 8192 floats = 24576 = 512*48)
        if (t < 48) f1f2[bid * 48 + t] = 0.f;
        // W2/W3 -> bf16 transposed (131072 elems = 512*256)
        {
            int idx = 131072 + bid * 256 + t;
            int within = idx & 65535;
            int n = within >> 8, k = within & 255;
            const float* W = ((idx >> 16) == 2) ? W2 : W3;
            Wbt[idx] = f2bf(W[k * 256 + n]);
        }
        // proj0: h1 = input @ W0 (32x64 tile, inline conversions)
        {
            unsigned short* As = (unsigned short*)smem;      // 32*264
            unsigned short* Bs = As + 32 * 264;              // 64*264
            const int m0 = (bid >> 2) * 32, n0 = (bid & 3) * 64;
            {
                int ar = t >> 3, ac0 = (t & 7) * 8;
                #pragma unroll
                for (int i = 0; i < 4; ++i) {
                    int col = ac0 + i * 64;
                    const float* src = &input[(size_t)(m0 + ar) * 256 + col];
                    ushort8v v;
                    #pragma unroll
                    for (int j = 0; j < 8; ++j) v[j] = f2bf(src[j]);
                    *(ushort8v*)&As[ar * 264 + col] = v;
                }
                #pragma unroll 8
                for (int it = 0; it < 64; ++it) {
                    int k = it * 4 + wave;
                    Bs[(t & 63) * 264 + k] = f2bf(W0[k * 256 + n0 + (t & 63)]);
                }
            }
            __syncthreads();
            const int wm = (wave >> 1) * 16, wn = (wave & 1) * 32;
            float4v acc[2] = {{0.f,0.f,0.f,0.f},{0.f,0.f,0.f,0.f}};
            #pragma unroll
            for (int kk = 0; kk < 256; kk += 32) {
                const int kc = kk + g * 8;
                short8 a = as_s8(*(const ushort8v*)&As[(wm + ml) * 264 + kc]);
                #pragma unroll
                for (int fn = 0; fn < 2; ++fn) {
                    short8 b = as_s8(*(const ushort8v*)&Bs[(wn + fn * 16 + ml) * 264 + kc]);
                    acc[fn] = __builtin_amdgcn_mfma_f32_16x16x32_bf16(a, b, acc[fn], 0, 0, 0);
                }
            }
            const int rb = wm + g * 4;
            #pragma unroll
            for (int fn = 0; fn < 2; ++fn)
                #pragma unroll
                for (int r = 0; r < 4; ++r)
                    h1[(size_t)(m0 + rb + r) * 256 + n0 + wn + fn * 16 + ml] = f2bf(acc[fn][r]);
        }
        // adj-pack: 8 rows/block (wave w -> rows bid*8 + w*2 + {0,1})
        {
            #pragma unroll 1
            for (int rr = 0; rr < 2; ++rr) {
                int row = bid * 8 + wave * 2 + rr;
                const int* arow = adj + (size_t)row * NN;
                #pragma unroll 8
                for (int seg = 0; seg < 64; ++seg) {
                    unsigned long long m = __ballot(arow[seg * 64 + lane] > 0);
                    if (lane == 0) bits[(size_t)row * WPR + seg] = m;
                }
            }
        }
    }
    gsync(bars + 0);

    //================= P1: proj1 (Whbt + f1f2 layer0) =================
    {
        unsigned short* As = (unsigned short*)smem;
        unsigned short* Bs = As + 32 * 264;
        const int m0 = (bid >> 2) * 32, n0 = (bid & 3) * 64;
        {
            int ar = t >> 3, ac0 = (t & 7) * 8;
            #pragma unroll
            for (int i = 0; i < 4; ++i) {
                int col = ac0 + i * 64;
                *(ushort8v*)&As[ar * 264 + col] = *(const ushort8v*)&h1[(size_t)(m0 + ar) * 256 + col];
            }
            #pragma unroll 8
            for (int it = 0; it < 64; ++it) {
                int k = it * 4 + wave;
                Bs[(t & 63) * 264 + k] = f2bf(W1[k * 256 + n0 + (t & 63)]);
            }
        }
        __syncthreads();
        const int wm = (wave >> 1) * 16, wn = (wave & 1) * 32;
        float4v acc[2] = {{0.f,0.f,0.f,0.f},{0.f,0.f,0.f,0.f}};
        #pragma unroll
        for (int kk = 0; kk < 256; kk += 32) {
            const int kc = kk + g * 8;
            short8 a = as_s8(*(const ushort8v*)&As[(wm + ml) * 264 + kc]);
            #pragma unroll
            for (int fn = 0; fn < 2; ++fn) {
                short8 b = as_s8(*(const ushort8v*)&Bs[(wn + fn * 16 + ml) * 264 + kc]);
                acc[fn] = __builtin_amdgcn_mfma_f32_16x16x32_bf16(a, b, acc[fn], 0, 0, 0);
            }
        }
        const int rb = wm + g * 4;
        {
            float a1c[2], a2c[2];
            #pragma unroll
            for (int fn = 0; fn < 2; ++fn) {
                a1c[fn] = a1v[n0 + wn + fn * 16 + ml];
                a2c[fn] = a1v[256 + n0 + wn + fn * 16 + ml];
            }
            #pragma unroll
            for (int r = 0; r < 4; ++r) {
                float s1 = acc[0][r] * a1c[0] + acc[1][r] * a1c[1];
                float s2 = acc[0][r] * a2c[0] + acc[1][r] * a2c[1];
                #pragma unroll
                for (int off = 1; off < 16; off <<= 1) {
                    s1 += __shfl_xor(s1, off, 64);
                    s2 += __shfl_xor(s2, off, 64);
                }
                if (ml == 0) {
                    int row = m0 + rb + r;
                    atomicAdd(&f1f2[row], s1);
                    atomicAdd(&f1f2[4096 + row], s2);
                }
            }
        }
        {
            unsigned short* T = As;
            __syncthreads();
            #pragma unroll
            for (int fn = 0; fn < 2; ++fn)
                #pragma unroll
                for (int r = 0; r < 4; ++r)
                    T[(wn + fn * 16 + ml) * 40 + rb + r] = f2bf(acc[fn][r]);
            __syncthreads();
            const int tr = t >> 2, tc = (t & 3) * 8;
            *(ushort8v*)&Whbt[(size_t)(n0 + tr) * 4096 + m0 + tc] = *(const ushort8v*)&T[tr * 40 + tc];
        }
    }
    gsync(bars + 1);

    //================= layers =================
    #pragma unroll 1
    for (int L = 0; L < 3; ++L) {
        float* f1f2L = f1f2 + L * 8192;

        if (L > 0) {
            //---- frp: reduce partials + ELU -> h -> GEMM -> Whbt + f1f2L ----
            if (bid < 256) {
                unsigned short* hA = (unsigned short*)smem;   // 16*280
                unsigned short* T  = hA + 16 * 280;           // 256*24
                const unsigned short* Bt = Wbt + ((L == 1) ? 2 : 3) * 65536;
                const float* av = (L == 1) ? a2v : a3v;
                const int m0 = bid * 16;

                const int bmP = m0 >> 7;
                const int wavea = (m0 >> 5) & 3;
                const int fmP = (m0 >> 4) & 1;
                const int bn = t >> 7, fnc = (t >> 4) & 7;
                const int widx = wavea * 16 + fmP * 8 + fnc;
                const size_t cbase = (size_t)(bmP * 2 + bn) * 16384 + (size_t)widx * 256 + (t & 15) * 16;
                float s[16];
                #pragma unroll
                for (int e = 0; e < 16; ++e) s[e] = 0.f;
                #pragma unroll
                for (int sp = 0; sp < 8; ++sp) {
                    const unsigned short* p = &parth[((size_t)sp << 20) + cbase];
                    ushort8v v0 = *(const ushort8v*)p;
                    ushort8v v1 = *(const ushort8v*)(p + 8);
                    #pragma unroll
                    for (int e = 0; e < 8; ++e) {
                        unsigned short u0 = v0[e], u1 = v1[e];
                        s[e]     += __half2float(*(__half*)&u0);
                        s[8 + e] += __half2float(*(__half*)&u1);
                    }
                }
                const int gq = (t & 15) >> 2;
                const int colb = bn * 128 + fnc * 16 + (t & 3) * 4;
                #pragma unroll
                for (int r = 0; r < 4; ++r) {
                    ushort4v w4;
                    #pragma unroll
                    for (int c = 0; c < 4; ++c) {
                        float x = s[c * 4 + r];
                        x = x > 0.f ? x : (__expf(x) - 1.f);
                        w4[c] = f2bf(x);
                    }
                    *(ushort4v*)&hA[(gq * 4 + r) * 280 + colb] = w4;
                }
                __syncthreads();

                float4v acc[4] = {{0.f,0.f,0.f,0.f},{0.f,0.f,0.f,0.f},{0.f,0.f,0.f,0.f},{0.f,0.f,0.f,0.f}};
                #pragma unroll
                for (int kk = 0; kk < 256; kk += 32) {
                    short8 a = as_s8(*(const ushort8v*)&hA[ml * 280 + kk + g * 8]);
                    #pragma unroll
                    for (int fn = 0; fn < 4; ++fn) {
                        short8 b = as_s8(*(const ushort8v*)&Bt[(size_t)(wave * 64 + fn * 16 + ml) * 256 + kk + g * 8]);
                        acc[fn] = __builtin_amdgcn_mfma_f32_16x16x32_bf16(a, b, acc[fn], 0, 0, 0);
                    }
                }
                {
                    float a1c[4], a2c[4];
                    #pragma unroll
                    for (int fn = 0; fn < 4; ++fn) {
                        int col = wave * 64 + fn * 16 + ml;
                        a1c[fn] = av[col];
                        a2c[fn] = av[256 + col];
                    }
                    #pragma unroll
                    for (int r = 0; r < 4; ++r) {
                        float s1 = acc[0][r] * a1c[0] + acc[1][r] * a1c[1] + acc[2][r] * a1c[2] + acc[3][r] * a1c[3];
                        float s2 = acc[0][r] * a2c[0] + acc[1][r] * a2c[1] + acc[2][r] * a2c[2] + acc[3][r] * a2c[3];
                        #pragma unroll
                        for (int off = 1; off < 16; off <<= 1) {
                            s1 += __shfl_xor(s1, off, 64);
                            s2 += __shfl_xor(s2, off, 64);
                        }
                        if (ml == 0) {
                            int row = m0 + g * 4 + r;
                            atomicAdd(&f1f2L[row], s1);
                            atomicAdd(&f1f2L[4096 + row], s2);
                        }
                    }
                }
                #pragma unroll
                for (int fn = 0; fn < 4; ++fn) {
                    int nl = wave * 64 + fn * 16 + ml;
                    ushort4v v4;
                    #pragma unroll
                    for (int r = 0; r < 4; ++r) v4[r] = f2bf(acc[fn][r]);
                    *(ushort4v*)&T[nl * 24 + g * 4] = v4;
                }
                __syncthreads();
                {
                    const int tn = t >> 1, half = t & 1;
                    #pragma unroll
                    for (int pass = 0; pass < 2; ++pass) {
                        int n = pass * 128 + tn;
                        *(ushort8v*)&Whbt[(size_t)n * 4096 + m0 + half * 8] = *(const ushort8v*)&T[n * 24 + half * 8];
                    }
                }
            }
            gsync(bars + 1 + 3 * L);
        }

        //---- rc: per-row coefficients + exp tables ----
        {
            float2* tl = (float2*)smem;   // 4096 * 8B = 32 KB
            const float* f2p = f1f2L + 4096;
            #pragma unroll
            for (int i = 0; i < 16; ++i) {
                float v = f2p[i * 256 + t];
                float2 pr = make_float2(__expf(v - C1), __expf(0.01f * v - C2));
                tl[i * 256 + t] = pr;
                if (bid == 0) tab2[i * 256 + t] = pr;
            }
            __syncthreads();
            for (int rr = 0; rr < 2; ++rr) {
                const int row = bid * 8 + wave * 2 + rr;
                const unsigned long long wl = bits[(size_t)row * WPR + lane];
                const float f1r = f1f2L[row];
                const float th = __expf(-f1r - C1);
                float mx = 0.f, S1 = 0.f, S2 = 0.f;
                #pragma unroll 16
                for (int b = 0; b < 64; ++b) {
                    unsigned long long w = __shfl(wl, b, 64);
                    bool bit = (w >> lane) & 1ULL;
                    float2 v = tl[b * 64 + lane];
                    float ebm = bit ? v.x : 0.f;
                    mx = fmaxf(mx, ebm);
                    bool cond = v.x > th;
                    S1 += (bit && cond)  ? v.x : 0.f;
                    S2 += (bit && !cond) ? v.y : 0.f;
                }
                #pragma unroll
                for (int off = 1; off < 64; off <<= 1) {
                    mx = fmaxf(mx, __shfl_xor(mx, off, 64));
                    S1 += __shfl_xor(S1, off, 64);
                    S2 += __shfl_xor(S2, off, 64);
                }
                if (lane == 0) {
                    float M  = C1 + __logf(mx);
                    float fm_ = f1r + M;
                    float m  = fm_ > 0.f ? fm_ : 0.01f * fm_;    // lrelu
                    float alpha = __expf(fminf(f1r + C1 - m, 60.f));
                    float gamma = __expf(fminf(0.01f * (f1r + C1) - m, 60.f));
                    float inv = 1.0f / (alpha * S1 + gamma * S2);
                    rowco[row] = make_float4(alpha * inv, gamma * inv, th, 0.f);
                }
            }
            // tl values are consumed only inside this phase (att uses global tab2)
        }
        gsync(bars + 2 + 3 * L);

        //---- att: masked-softmax GEMM, NSTEPS=16 (SPLIT=8), swizzled DMA k-chunks ----
        {
            constexpr int NSTEPS = 16;
            const float* tab2f = (const float*)tab2;
            unsigned short* BsA = (unsigned short*)smem;   // [2][128*32] = 16 KB
            const int bm = bid & 31;
            const int bn = (bid >> 5) & 1;
            const int ks = bid >> 6;
            const int m0 = bm * 128, n0 = bn * 128;
            const int k0 = ks * (NSTEPS * 32);

            const int drow = lane >> 2, dcol = ((lane & 3) ^ (lane >> 4)) * 8;
            const unsigned short* dsrc0 = Whbt + (size_t)(n0 + wave * 16 + drow) * 4096 + dcol;
            const unsigned short* dsrc1 = dsrc0 + (size_t)64 * 4096;
            unsigned short* dst0  = BsA + wave * 512;
            unsigned short* dst1  = BsA + 2048 + wave * 512;
            unsigned short* dst0b = BsA + 4096 + wave * 512;
            unsigned short* dst1b = BsA + 4096 + 2048 + wave * 512;

            float pA[2], pG[2];
            unsigned long long wpre[2][NSTEPS / 2];
            #pragma unroll
            for (int fm = 0; fm < 2; ++fm) {
                int row = m0 + wave * 32 + fm * 16 + ml;
                float4 rc4 = rowco[row];
                pA[fm] = rc4.x; pG[fm] = rc4.y;
                const unsigned long long* brow = bits + (size_t)row * WPR + (k0 >> 6);
                #pragma unroll
                for (int w = 0; w < NSTEPS / 2; ++w) wpre[fm][w] = brow[w];
            }

            float4v acc[2][8];
            #pragma unroll
            for (int i = 0; i < 2; ++i)
                #pragma unroll
                for (int j = 0; j < 8; ++j) acc[i][j] = (float4v){0.f, 0.f, 0.f, 0.f};

            float4v tq0, tq1, tq2, tq3;
            {
                gl_lds16(dsrc0 + k0, dst0);
                gl_lds16(dsrc1 + k0, dst1);
                const float4v* q = (const float4v*)&tab2f[2 * (k0 + g * 8)];
                tq0 = q[0]; tq1 = q[1]; tq2 = q[2]; tq3 = q[3];
            }
            __syncthreads();

            const int rdoff = ((g ^ (ml >> 2)) & 3) * 8;

            #pragma unroll
            for (int i = 0; i < NSTEPS; ++i) {
                const int kk = k0 + i * 32;
                const int p = i & 1;
                float4v nt0, nt1, nt2, nt3;
                if (i + 1 < NSTEPS) {
                    gl_lds16(dsrc0 + kk + 32, p ? dst0 : dst0b);
                    gl_lds16(dsrc1 + kk + 32, p ? dst1 : dst1b);
                    const float4v* q = (const float4v*)&tab2f[2 * (kk + 32 + g * 8)];
                    nt0 = q[0]; nt1 = q[1]; nt2 = q[2]; nt3 = q[3];
                }
                const int sh = (i & 1) * 32 + g * 8;
                short8 afr[2];
                #pragma unroll
                for (int fm = 0; fm < 2; ++fm) {
                    unsigned int wh = (unsigned int)(wpre[fm][i >> 1] >> sh);
                    ushort8v af;
                    #pragma unroll
                    for (int jj = 0; jj < 4; ++jj) {
                        float4v v = (jj == 0) ? tq0 : (jj == 1) ? tq1 : (jj == 2) ? tq2 : tq3;
                        float x0 = fmaxf(pA[fm] * v[0], pG[fm] * v[1]);
                        float x1 = fmaxf(pA[fm] * v[2], pG[fm] * v[3]);
                        x0 = ((wh >> (2 * jj)) & 1u)     ? x0 : 0.f;
                        x1 = ((wh >> (2 * jj + 1)) & 1u) ? x1 : 0.f;
                        union { __hip_bfloat162 b2; unsigned int u; } cv;
                        cv.b2 = __float22bfloat162_rn(make_float2(x0, x1));
                        ((unsigned int*)&af)[jj] = cv.u;
                    }
                    afr[fm] = as_s8(af);
                }
                #pragma unroll
                for (int fn = 0; fn < 8; ++fn) {
                    short8 b = as_s8(*(const ushort8v*)&BsA[p * 4096 + (fn * 16 + ml) * 32 + rdoff]);
                    acc[0][fn] = __builtin_amdgcn_mfma_f32_16x16x32_bf16(afr[0], b, acc[0][fn], 0, 0, 0);
                    acc[1][fn] = __builtin_amdgcn_mfma_f32_16x16x32_bf16(afr[1], b, acc[1][fn], 0, 0, 0);
                }
                if (i + 1 < NSTEPS) {
                    __syncthreads();
                    tq0 = nt0; tq1 = nt1; tq2 = nt2; tq3 = nt3;
                }
            }

            unsigned short* pbase = parth + ((size_t)ks << 20) + (size_t)(bm * 2 + bn) * 16384;
            #pragma unroll
            for (int fm = 0; fm < 2; ++fm)
                #pragma unroll
                for (int fn = 0; fn < 8; ++fn) {
                    ushort4v v4;
                    #pragma unroll
                    for (int r = 0; r < 4; ++r) {
                        __half h = __float2half(acc[fm][fn][r]);
                        v4[r] = *(unsigned short*)&h;
                    }
                    *(ushort4v*)&pbase[((wave * 16 + fm * 8 + fn) * 64 + lane) * 4] = v4;
                }
        }
        gsync(bars + 3 + 3 * L);
    }

    //================= rout =================
    {
        const int flat = (bid * 256 + t) * 8;
        float s[8] = {0.f, 0.f, 0.f, 0.f, 0.f, 0.f, 0.f, 0.f};
        #pragma unroll
        for (int sp = 0; sp < 8; ++sp) {
            ushort8v v = *(const ushort8v*)&parth[((size_t)sp << 20) + flat];
            #pragma unroll
            for (int j = 0; j < 8; ++j) {
                unsigned short u = v[j];
                s[j] += __half2float(*(__half*)&u);
            }
        }
        const int tile  = flat >> 14;
        const int inner = flat & 16383;
        const int widx = inner >> 8;
        const int ls   = (inner >> 2) & 63;
        const int bm = tile >> 1, bn = tile & 1;
        const int wavea = widx >> 4, fm = (widx >> 3) & 1, fn = widx & 7;
        const int gg = ls >> 4, mll = ls & 15;
        const int row0 = bm * 128 + wavea * 32 + fm * 16 + gg * 4;
        const int col  = bn * 128 + fn * 16 + mll;
        #pragma unroll
        for (int r = 0; r < 4; ++r) {
            float x0 = s[r];
            float x1 = s[4 + r];
            x0 = x0 > 0.f ? x0 : (__expf(x0) - 1.f);
            x1 = x1 > 0.f ? x1 : (__expf(x1) - 1.f);
            *(float2*)&out[(size_t)(row0 + r) * 256 + col] = make_float2(x0, x1);
        }
    }
}

extern "C" void kernel_launch(void* const* d_in, const int* in_sizes, int n_in,
                              void* d_out, int out_size, void* d_ws, size_t ws_size,
                              hipStream_t stream) {
    const float* input = (const float*)d_in[0];
    const int*   adj   = (const int*)d_in[1];
    const float* W0    = (const float*)d_in[2];
    const float* W1    = (const float*)d_in[3];
    const float* a1    = (const float*)d_in[4];
    const float* W2    = (const float*)d_in[5];
    const float* a2    = (const float*)d_in[6];
    const float* W3    = (const float*)d_in[7];
    const float* a3    = (const float*)d_in[8];
    float* out = (float*)d_out;
    char* ws = (char*)d_ws;

    unsigned long long* bits = (unsigned long long*)(ws);                 // 2 MB
    unsigned short* h1   = (unsigned short*)(ws + (4u << 20));            // 2 MB
    unsigned short* Whbt = (unsigned short*)(ws + (6u << 20));            // 2 MB
    unsigned short* Wbt  = (unsigned short*)(ws + (8u << 20));            // 512 KB
    float*  f1f2  = (float*)(ws + (9u << 20));                            // 3 layers x 32 KB
    float4* rowco = (float4*)(ws + (10u << 20));                          // 64 KB
    float2* tab2  = (float2*)(ws + (10u << 20) + (256u << 10));           // 32 KB
    unsigned* bars = (unsigned*)(ws + (12u << 20));                       // 10 sync counters
    unsigned short* parth = (unsigned short*)(ws + (13u << 20));          // 8 x 2 MB (fp16)
    (void)ws_size;

    hipMemsetAsync(bars, 0, 64, stream);
    mega<<<NBLK, 256, 0, stream>>>(input, adj, W0, W1, a1, W2, a2, W3, a3, out,
                                   bits, h1, Whbt, Wbt, f1f2, rowco, tab2, parth, bars);
}

// Round 4
// 1054.729 us; speedup vs baseline: 1.6023x; 1.6023x over previous
//
#include <hip/hip_runtime.h>
#include <hip/hip_bf16.h>
#include <hip/hip_fp16.h>
#include <cstdint>
#include <cstddef>

#define NN 4096
#define WPR 64   // 64-bit words per adjacency row
#define NBLK 512 // persistent grid: 2 blocks/CU on 256 CUs, co-resident by construction

typedef __attribute__((ext_vector_type(8))) unsigned short ushort8v;
typedef __attribute__((ext_vector_type(4))) unsigned short ushort4v;
typedef __attribute__((ext_vector_type(8))) short short8;
typedef __attribute__((ext_vector_type(4))) float float4v;

#define C1 30.0f
#define C2 0.3f    // 0.01 * C1

static __device__ __forceinline__ unsigned short f2bf(float x) {
    union { float f; unsigned int u; } v; v.f = x;
    unsigned int r = v.u + 0x7FFFu + ((v.u >> 16) & 1u);
    return (unsigned short)(r >> 16);
}

static __device__ __forceinline__ short8 as_s8(ushort8v v) {
    union { ushort8v u; short8 s; } x; x.u = v; return x.s;
}

// async 16B/lane global -> LDS DMA (wave-uniform LDS base + lane*16)
static __device__ __forceinline__ void gl_lds16(const unsigned short* g, unsigned short* l) {
    __builtin_amdgcn_global_load_lds(
        (const __attribute__((address_space(1))) unsigned int*)g,
        (__attribute__((address_space(3))) unsigned int*)l,
        16, 0, 0);
}

// grid-wide barrier, R4 fix: RELAXED spin (plain coherent load, NO per-iteration
// cache invalidate). Acquire/release fences exactly once per barrier:
//   release threadfence -> relaxed arrive -> relaxed spin -> block barrier -> acquire threadfence.
// R3's ACQUIRE-spin emitted buffer_inv every poll iteration from up to 512 leader
// waves -> continuous L1/L2 invalidation storm -> whole kernel latency-bound (6x).
static __device__ __forceinline__ void gsync(unsigned* bar) {
    __syncthreads();
    if (threadIdx.x == 0) {
        __threadfence();   // release: writeback this block's stores to coherent point
        __hip_atomic_fetch_add(bar, 1u, __ATOMIC_RELAXED, __HIP_MEMORY_SCOPE_AGENT);
        while (__hip_atomic_load(bar, __ATOMIC_RELAXED, __HIP_MEMORY_SCOPE_AGENT) < NBLK)
            __builtin_amdgcn_s_sleep(2);
    }
    __syncthreads();
    __threadfence();       // acquire: invalidate stale L1/L2 lines once
}

// ============================ the whole GAT in one dispatch ============================
// Phases (10 grid syncs):
//  P0 : proj0 (h1 = input @ W0, inline fp32->bf16) + adj-pack + W2/W3 cvt + f1f2 zero
//  P1 : proj1 (Whbt/f1f2_0 = h1 @ W1, inline W1 cvt)
//  per layer L=0..2:  [L>0: frp]  -> rc -> att
//  tail: rout
__global__ __launch_bounds__(256, 2) void mega(
    const float* __restrict__ input, const int* __restrict__ adj,
    const float* __restrict__ W0, const float* __restrict__ W1,
    const float* __restrict__ a1v, const float* __restrict__ W2,
    const float* __restrict__ a2v, const float* __restrict__ W3,
    const float* __restrict__ a3v, float* __restrict__ out,
    unsigned long long* bits, unsigned short* h1, unsigned short* Whbt,
    unsigned short* Wbt, float* f1f2, float4* rowco, float2* tab2,
    unsigned short* parth, unsigned* bars)
{
    const int bid = blockIdx.x;
    const int t = threadIdx.x;
    const int lane = t & 63, wave = t >> 6;
    const int g = lane >> 4, ml = lane & 15;
    __shared__ __align__(16) char smem[50688];   // max over phases (proj: 50688)

    //================= P0 =================
    {
        // zero f1f2 (3 layers x 8192 floats = 24576 = 512*48)
        if (t < 48) f1f2[bid * 48 + t] = 0.f;
        // W2/W3 -> bf16 transposed (131072 elems = 512*256)
        {
            int idx = 131072 + bid * 256 + t;
            int within = idx & 65535;
            int n = within >> 8, k = within & 255;
            const float* W = ((idx >> 16) == 2) ? W2 : W3;
            Wbt[idx] = f2bf(W[k * 256 + n]);
        }
        // proj0: h1 = input @ W0 (32x64 tile, inline conversions)
        {
            unsigned short* As = (unsigned short*)smem;      // 32*264
            unsigned short* Bs = As + 32 * 264;              // 64*264
            const int m0 = (bid >> 2) * 32, n0 = (bid & 3) * 64;
            {
                int ar = t >> 3, ac0 = (t & 7) * 8;
                #pragma unroll
                for (int i = 0; i < 4; ++i) {
                    int col = ac0 + i * 64;
                    const float* src = &input[(size_t)(m0 + ar) * 256 + col];
                    ushort8v v;
                    #pragma unroll
                    for (int j = 0; j < 8; ++j) v[j] = f2bf(src[j]);
                    *(ushort8v*)&As[ar * 264 + col] = v;
                }
                #pragma unroll 8
                for (int it = 0; it < 64; ++it) {
                    int k = it * 4 + wave;
                    Bs[(t & 63) * 264 + k] = f2bf(W0[k * 256 + n0 + (t & 63)]);
                }
            }
            __syncthreads();
            const int wm = (wave >> 1) * 16, wn = (wave & 1) * 32;
            float4v acc[2] = {{0.f,0.f,0.f,0.f},{0.f,0.f,0.f,0.f}};
            #pragma unroll
            for (int kk = 0; kk < 256; kk += 32) {
                const int kc = kk + g * 8;
                short8 a = as_s8(*(const ushort8v*)&As[(wm + ml) * 264 + kc]);
                #pragma unroll
                for (int fn = 0; fn < 2; ++fn) {
                    short8 b = as_s8(*(const ushort8v*)&Bs[(wn + fn * 16 + ml) * 264 + kc]);
                    acc[fn] = __builtin_amdgcn_mfma_f32_16x16x32_bf16(a, b, acc[fn], 0, 0, 0);
                }
            }
            const int rb = wm + g * 4;
            #pragma unroll
            for (int fn = 0; fn < 2; ++fn)
                #pragma unroll
                for (int r = 0; r < 4; ++r)
                    h1[(size_t)(m0 + rb + r) * 256 + n0 + wn + fn * 16 + ml] = f2bf(acc[fn][r]);
        }
        // adj-pack: 8 rows/block (wave w -> rows bid*8 + w*2 + {0,1})
        {
            #pragma unroll 1
            for (int rr = 0; rr < 2; ++rr) {
                int row = bid * 8 + wave * 2 + rr;
                const int* arow = adj + (size_t)row * NN;
                #pragma unroll 8
                for (int seg = 0; seg < 64; ++seg) {
                    unsigned long long m = __ballot(arow[seg * 64 + lane] > 0);
                    if (lane == 0) bits[(size_t)row * WPR + seg] = m;
                }
            }
        }
    }
    gsync(bars + 0);

    //================= P1: proj1 (Whbt + f1f2 layer0) =================
    {
        unsigned short* As = (unsigned short*)smem;
        unsigned short* Bs = As + 32 * 264;
        const int m0 = (bid >> 2) * 32, n0 = (bid & 3) * 64;
        {
            int ar = t >> 3, ac0 = (t & 7) * 8;
            #pragma unroll
            for (int i = 0; i < 4; ++i) {
                int col = ac0 + i * 64;
                *(ushort8v*)&As[ar * 264 + col] = *(const ushort8v*)&h1[(size_t)(m0 + ar) * 256 + col];
            }
            #pragma unroll 8
            for (int it = 0; it < 64; ++it) {
                int k = it * 4 + wave;
                Bs[(t & 63) * 264 + k] = f2bf(W1[k * 256 + n0 + (t & 63)]);
            }
        }
        __syncthreads();
        const int wm = (wave >> 1) * 16, wn = (wave & 1) * 32;
        float4v acc[2] = {{0.f,0.f,0.f,0.f},{0.f,0.f,0.f,0.f}};
        #pragma unroll
        for (int kk = 0; kk < 256; kk += 32) {
            const int kc = kk + g * 8;
            short8 a = as_s8(*(const ushort8v*)&As[(wm + ml) * 264 + kc]);
            #pragma unroll
            for (int fn = 0; fn < 2; ++fn) {
                short8 b = as_s8(*(const ushort8v*)&Bs[(wn + fn * 16 + ml) * 264 + kc]);
                acc[fn] = __builtin_amdgcn_mfma_f32_16x16x32_bf16(a, b, acc[fn], 0, 0, 0);
            }
        }
        const int rb = wm + g * 4;
        {
            float a1c[2], a2c[2];
            #pragma unroll
            for (int fn = 0; fn < 2; ++fn) {
                a1c[fn] = a1v[n0 + wn + fn * 16 + ml];
                a2c[fn] = a1v[256 + n0 + wn + fn * 16 + ml];
            }
            #pragma unroll
            for (int r = 0; r < 4; ++r) {
                float s1 = acc[0][r] * a1c[0] + acc[1][r] * a1c[1];
                float s2 = acc[0][r] * a2c[0] + acc[1][r] * a2c[1];
                #pragma unroll
                for (int off = 1; off < 16; off <<= 1) {
                    s1 += __shfl_xor(s1, off, 64);
                    s2 += __shfl_xor(s2, off, 64);
                }
                if (ml == 0) {
                    int row = m0 + rb + r;
                    atomicAdd(&f1f2[row], s1);
                    atomicAdd(&f1f2[4096 + row], s2);
                }
            }
        }
        {
            unsigned short* T = As;
            __syncthreads();
            #pragma unroll
            for (int fn = 0; fn < 2; ++fn)
                #pragma unroll
                for (int r = 0; r < 4; ++r)
                    T[(wn + fn * 16 + ml) * 40 + rb + r] = f2bf(acc[fn][r]);
            __syncthreads();
            const int tr = t >> 2, tc = (t & 3) * 8;
            *(ushort8v*)&Whbt[(size_t)(n0 + tr) * 4096 + m0 + tc] = *(const ushort8v*)&T[tr * 40 + tc];
        }
    }
    gsync(bars + 1);

    //================= layers =================
    #pragma unroll 1
    for (int L = 0; L < 3; ++L) {
        float* f1f2L = f1f2 + L * 8192;

        if (L > 0) {
            //---- frp: reduce partials + ELU -> h -> GEMM -> Whbt + f1f2L ----
            if (bid < 256) {
                unsigned short* hA = (unsigned short*)smem;   // 16*280
                unsigned short* T  = hA + 16 * 280;           // 256*24
                const unsigned short* Bt = Wbt + ((L == 1) ? 2 : 3) * 65536;
                const float* av = (L == 1) ? a2v : a3v;
                const int m0 = bid * 16;

                const int bmP = m0 >> 7;
                const int wavea = (m0 >> 5) & 3;
                const int fmP = (m0 >> 4) & 1;
                const int bn = t >> 7, fnc = (t >> 4) & 7;
                const int widx = wavea * 16 + fmP * 8 + fnc;
                const size_t cbase = (size_t)(bmP * 2 + bn) * 16384 + (size_t)widx * 256 + (t & 15) * 16;
                float s[16];
                #pragma unroll
                for (int e = 0; e < 16; ++e) s[e] = 0.f;
                #pragma unroll
                for (int sp = 0; sp < 8; ++sp) {
                    const unsigned short* p = &parth[((size_t)sp << 20) + cbase];
                    ushort8v v0 = *(const ushort8v*)p;
                    ushort8v v1 = *(const ushort8v*)(p + 8);
                    #pragma unroll
                    for (int e = 0; e < 8; ++e) {
                        unsigned short u0 = v0[e], u1 = v1[e];
                        s[e]     += __half2float(*(__half*)&u0);
                        s[8 + e] += __half2float(*(__half*)&u1);
                    }
                }
                const int gq = (t & 15) >> 2;
                const int colb = bn * 128 + fnc * 16 + (t & 3) * 4;
                #pragma unroll
                for (int r = 0; r < 4; ++r) {
                    ushort4v w4;
                    #pragma unroll
                    for (int c = 0; c < 4; ++c) {
                        float x = s[c * 4 + r];
                        x = x > 0.f ? x : (__expf(x) - 1.f);
                        w4[c] = f2bf(x);
                    }
                    *(ushort4v*)&hA[(gq * 4 + r) * 280 + colb] = w4;
                }
                __syncthreads();

                float4v acc[4] = {{0.f,0.f,0.f,0.f},{0.f,0.f,0.f,0.f},{0.f,0.f,0.f,0.f},{0.f,0.f,0.f,0.f}};
                #pragma unroll
                for (int kk = 0; kk < 256; kk += 32) {
                    short8 a = as_s8(*(const ushort8v*)&hA[ml * 280 + kk + g * 8]);
                    #pragma unroll
                    for (int fn = 0; fn < 4; ++fn) {
                        short8 b = as_s8(*(const ushort8v*)&Bt[(size_t)(wave * 64 + fn * 16 + ml) * 256 + kk + g * 8]);
                        acc[fn] = __builtin_amdgcn_mfma_f32_16x16x32_bf16(a, b, acc[fn], 0, 0, 0);
                    }
                }
                {
                    float a1c[4], a2c[4];
                    #pragma unroll
                    for (int fn = 0; fn < 4; ++fn) {
                        int col = wave * 64 + fn * 16 + ml;
                        a1c[fn] = av[col];
                        a2c[fn] = av[256 + col];
                    }
                    #pragma unroll
                    for (int r = 0; r < 4; ++r) {
                        float s1 = acc[0][r] * a1c[0] + acc[1][r] * a1c[1] + acc[2][r] * a1c[2] + acc[3][r] * a1c[3];
                        float s2 = acc[0][r] * a2c[0] + acc[1][r] * a2c[1] + acc[2][r] * a2c[2] + acc[3][r] * a2c[3];
                        #pragma unroll
                        for (int off = 1; off < 16; off <<= 1) {
                            s1 += __shfl_xor(s1, off, 64);
                            s2 += __shfl_xor(s2, off, 64);
                        }
                        if (ml == 0) {
                            int row = m0 + g * 4 + r;
                            atomicAdd(&f1f2L[row], s1);
                            atomicAdd(&f1f2L[4096 + row], s2);
                        }
                    }
                }
                #pragma unroll
                for (int fn = 0; fn < 4; ++fn) {
                    int nl = wave * 64 + fn * 16 + ml;
                    ushort4v v4;
                    #pragma unroll
                    for (int r = 0; r < 4; ++r) v4[r] = f2bf(acc[fn][r]);
                    *(ushort4v*)&T[nl * 24 + g * 4] = v4;
                }
                __syncthreads();
                {
                    const int tn = t >> 1, half = t & 1;
                    #pragma unroll
                    for (int pass = 0; pass < 2; ++pass) {
                        int n = pass * 128 + tn;
                        *(ushort8v*)&Whbt[(size_t)n * 4096 + m0 + half * 8] = *(const ushort8v*)&T[n * 24 + half * 8];
                    }
                }
            }
            gsync(bars + 1 + 3 * L);
        }

        //---- rc: per-row coefficients + exp tables ----
        {
            float2* tl = (float2*)smem;   // 4096 * 8B = 32 KB
            const float* f2p = f1f2L + 4096;
            #pragma unroll
            for (int i = 0; i < 16; ++i) {
                float v = f2p[i * 256 + t];
                float2 pr = make_float2(__expf(v - C1), __expf(0.01f * v - C2));
                tl[i * 256 + t] = pr;
                if (bid == 0) tab2[i * 256 + t] = pr;
            }
            __syncthreads();
            for (int rr = 0; rr < 2; ++rr) {
                const int row = bid * 8 + wave * 2 + rr;
                const unsigned long long wl = bits[(size_t)row * WPR + lane];
                const float f1r = f1f2L[row];
                const float th = __expf(-f1r - C1);
                float mx = 0.f, S1 = 0.f, S2 = 0.f;
                #pragma unroll 16
                for (int b = 0; b < 64; ++b) {
                    unsigned long long w = __shfl(wl, b, 64);
                    bool bit = (w >> lane) & 1ULL;
                    float2 v = tl[b * 64 + lane];
                    float ebm = bit ? v.x : 0.f;
                    mx = fmaxf(mx, ebm);
                    bool cond = v.x > th;
                    S1 += (bit && cond)  ? v.x : 0.f;
                    S2 += (bit && !cond) ? v.y : 0.f;
                }
                #pragma unroll
                for (int off = 1; off < 64; off <<= 1) {
                    mx = fmaxf(mx, __shfl_xor(mx, off, 64));
                    S1 += __shfl_xor(S1, off, 64);
                    S2 += __shfl_xor(S2, off, 64);
                }
                if (lane == 0) {
                    float M  = C1 + __logf(mx);
                    float fm_ = f1r + M;
                    float m  = fm_ > 0.f ? fm_ : 0.01f * fm_;    // lrelu
                    float alpha = __expf(fminf(f1r + C1 - m, 60.f));
                    float gamma = __expf(fminf(0.01f * (f1r + C1) - m, 60.f));
                    float inv = 1.0f / (alpha * S1 + gamma * S2);
                    rowco[row] = make_float4(alpha * inv, gamma * inv, th, 0.f);
                }
            }
            // tl values are consumed only inside this phase (att uses global tab2)
        }
        gsync(bars + 2 + 3 * L);

        //---- att: masked-softmax GEMM, NSTEPS=16 (SPLIT=8), swizzled DMA k-chunks ----
        {
            constexpr int NSTEPS = 16;
            const float* tab2f = (const float*)tab2;
            unsigned short* BsA = (unsigned short*)smem;   // [2][128*32] = 16 KB
            const int bm = bid & 31;
            const int bn = (bid >> 5) & 1;
            const int ks = bid >> 6;
            const int m0 = bm * 128, n0 = bn * 128;
            const int k0 = ks * (NSTEPS * 32);

            const int drow = lane >> 2, dcol = ((lane & 3) ^ (lane >> 4)) * 8;
            const unsigned short* dsrc0 = Whbt + (size_t)(n0 + wave * 16 + drow) * 4096 + dcol;
            const unsigned short* dsrc1 = dsrc0 + (size_t)64 * 4096;
            unsigned short* dst0  = BsA + wave * 512;
            unsigned short* dst1  = BsA + 2048 + wave * 512;
            unsigned short* dst0b = BsA + 4096 + wave * 512;
            unsigned short* dst1b = BsA + 4096 + 2048 + wave * 512;

            float pA[2], pG[2];
            unsigned long long wpre[2][NSTEPS / 2];
            #pragma unroll
            for (int fm = 0; fm < 2; ++fm) {
                int row = m0 + wave * 32 + fm * 16 + ml;
                float4 rc4 = rowco[row];
                pA[fm] = rc4.x; pG[fm] = rc4.y;
                const unsigned long long* brow = bits + (size_t)row * WPR + (k0 >> 6);
                #pragma unroll
                for (int w = 0; w < NSTEPS / 2; ++w) wpre[fm][w] = brow[w];
            }

            float4v acc[2][8];
            #pragma unroll
            for (int i = 0; i < 2; ++i)
                #pragma unroll
                for (int j = 0; j < 8; ++j) acc[i][j] = (float4v){0.f, 0.f, 0.f, 0.f};

            float4v tq0, tq1, tq2, tq3;
            {
                gl_lds16(dsrc0 + k0, dst0);
                gl_lds16(dsrc1 + k0, dst1);
                const float4v* q = (const float4v*)&tab2f[2 * (k0 + g * 8)];
                tq0 = q[0]; tq1 = q[1]; tq2 = q[2]; tq3 = q[3];
            }
            __syncthreads();

            const int rdoff = ((g ^ (ml >> 2)) & 3) * 8;

            #pragma unroll
            for (int i = 0; i < NSTEPS; ++i) {
                const int kk = k0 + i * 32;
                const int p = i & 1;
                float4v nt0, nt1, nt2, nt3;
                if (i + 1 < NSTEPS) {
                    gl_lds16(dsrc0 + kk + 32, p ? dst0 : dst0b);
                    gl_lds16(dsrc1 + kk + 32, p ? dst1 : dst1b);
                    const float4v* q = (const float4v*)&tab2f[2 * (kk + 32 + g * 8)];
                    nt0 = q[0]; nt1 = q[1]; nt2 = q[2]; nt3 = q[3];
                }
                const int sh = (i & 1) * 32 + g * 8;
                short8 afr[2];
                #pragma unroll
                for (int fm = 0; fm < 2; ++fm) {
                    unsigned int wh = (unsigned int)(wpre[fm][i >> 1] >> sh);
                    ushort8v af;
                    #pragma unroll
                    for (int jj = 0; jj < 4; ++jj) {
                        float4v v = (jj == 0) ? tq0 : (jj == 1) ? tq1 : (jj == 2) ? tq2 : tq3;
                        float x0 = fmaxf(pA[fm] * v[0], pG[fm] * v[1]);
                        float x1 = fmaxf(pA[fm] * v[2], pG[fm] * v[3]);
                        x0 = ((wh >> (2 * jj)) & 1u)     ? x0 : 0.f;
                        x1 = ((wh >> (2 * jj + 1)) & 1u) ? x1 : 0.f;
                        union { __hip_bfloat162 b2; unsigned int u; } cv;
                        cv.b2 = __float22bfloat162_rn(make_float2(x0, x1));
                        ((unsigned int*)&af)[jj] = cv.u;
                    }
                    afr[fm] = as_s8(af);
                }
                #pragma unroll
                for (int fn = 0; fn < 8; ++fn) {
                    short8 b = as_s8(*(const ushort8v*)&BsA[p * 4096 + (fn * 16 + ml) * 32 + rdoff]);
                    acc[0][fn] = __builtin_amdgcn_mfma_f32_16x16x32_bf16(afr[0], b, acc[0][fn], 0, 0, 0);
                    acc[1][fn] = __builtin_amdgcn_mfma_f32_16x16x32_bf16(afr[1], b, acc[1][fn], 0, 0, 0);
                }
                if (i + 1 < NSTEPS) {
                    __syncthreads();
                    tq0 = nt0; tq1 = nt1; tq2 = nt2; tq3 = nt3;
                }
            }

            unsigned short* pbase = parth + ((size_t)ks << 20) + (size_t)(bm * 2 + bn) * 16384;
            #pragma unroll
            for (int fm = 0; fm < 2; ++fm)
                #pragma unroll
                for (int fn = 0; fn < 8; ++fn) {
                    ushort4v v4;
                    #pragma unroll
                    for (int r = 0; r < 4; ++r) {
                        __half h = __float2half(acc[fm][fn][r]);
                        v4[r] = *(unsigned short*)&h;
                    }
                    *(ushort4v*)&pbase[((wave * 16 + fm * 8 + fn) * 64 + lane) * 4] = v4;
                }
        }
        gsync(bars + 3 + 3 * L);
    }

    //================= rout =================
    {
        const int flat = (bid * 256 + t) * 8;
        float s[8] = {0.f, 0.f, 0.f, 0.f, 0.f, 0.f, 0.f, 0.f};
        #pragma unroll
        for (int sp = 0; sp < 8; ++sp) {
            ushort8v v = *(const ushort8v*)&parth[((size_t)sp << 20) + flat];
            #pragma unroll
            for (int j = 0; j < 8; ++j) {
                unsigned short u = v[j];
                s[j] += __half2float(*(__half*)&u);
            }
        }
        const int tile  = flat >> 14;
        const int inner = flat & 16383;
        const int widx = inner >> 8;
        const int ls   = (inner >> 2) & 63;
        const int bm = tile >> 1, bn = tile & 1;
        const int wavea = widx >> 4, fm = (widx >> 3) & 1, fn = widx & 7;
        const int gg = ls >> 4, mll = ls & 15;
        const int row0 = bm * 128 + wavea * 32 + fm * 16 + gg * 4;
        const int col  = bn * 128 + fn * 16 + mll;
        #pragma unroll
        for (int r = 0; r < 4; ++r) {
            float x0 = s[r];
            float x1 = s[4 + r];
            x0 = x0 > 0.f ? x0 : (__expf(x0) - 1.f);
            x1 = x1 > 0.f ? x1 : (__expf(x1) - 1.f);
            *(float2*)&out[(size_t)(row0 + r) * 256 + col] = make_float2(x0, x1);
        }
    }
}

extern "C" void kernel_launch(void* const* d_in, const int* in_sizes, int n_in,
                              void* d_out, int out_size, void* d_ws, size_t ws_size,
                              hipStream_t stream) {
    const float* input = (const float*)d_in[0];
    const int*   adj   = (const int*)d_in[1];
    const float* W0    = (const float*)d_in[2];
    const float* W1    = (const float*)d_in[3];
    const float* a1    = (const float*)d_in[4];
    const float* W2    = (const float*)d_in[5];
    const float* a2    = (const float*)d_in[6];
    const float* W3    = (const float*)d_in[7];
    const float* a3    = (const float*)d_in[8];
    float* out = (float*)d_out;
    char* ws = (char*)d_ws;

    unsigned long long* bits = (unsigned long long*)(ws);                 // 2 MB
    unsigned short* h1   = (unsigned short*)(ws + (4u << 20));            // 2 MB
    unsigned short* Whbt = (unsigned short*)(ws + (6u << 20));            // 2 MB
    unsigned short* Wbt  = (unsigned short*)(ws + (8u << 20));            // 512 KB
    float*  f1f2  = (float*)(ws + (9u << 20));                            // 3 layers x 32 KB
    float4* rowco = (float4*)(ws + (10u << 20));                          // 64 KB
    float2* tab2  = (float2*)(ws + (10u << 20) + (256u << 10));           // 32 KB
    unsigned* bars = (unsigned*)(ws + (12u << 20));                       // 10 sync counters
    unsigned short* parth = (unsigned short*)(ws + (13u << 20));          // 8 x 2 MB (fp16)
    (void)ws_size;

    hipMemsetAsync(bars, 0, 64, stream);
    mega<<<NBLK, 256, 0, stream>>>(input, adj, W0, W1, a1, W2, a2, W3, a3, out,
                                   bits, h1, Whbt, Wbt, f1f2, rowco, tab2, parth, bars);
}

// Round 5
// 311.103 us; speedup vs baseline: 5.4323x; 3.3903x over previous
//
#include <hip/hip_runtime.h>
#include <hip/hip_bf16.h>
#include <hip/hip_fp16.h>
#include <cstdint>
#include <cstddef>

#define NN 4096
#define WPR 64  // 64-bit words per adjacency row

typedef __attribute__((ext_vector_type(8))) unsigned short ushort8v;
typedef __attribute__((ext_vector_type(4))) unsigned short ushort4v;
typedef __attribute__((ext_vector_type(8))) short short8;
typedef __attribute__((ext_vector_type(4))) float float4v;

#define C1 30.0f
#define C2 0.3f    // 0.01 * C1

static __device__ __forceinline__ unsigned short f2bf(float x) {
    union { float f; unsigned int u; } v; v.f = x;
    unsigned int r = v.u + 0x7FFFu + ((v.u >> 16) & 1u);
    return (unsigned short)(r >> 16);
}

static __device__ __forceinline__ short8 as_s8(ushort8v v) {
    union { ushort8v u; short8 s; } x; x.u = v; return x.s;
}

// async 16B/lane global -> LDS DMA (wave-uniform LDS base + lane*16)
static __device__ __forceinline__ void gl_lds16(const unsigned short* g, unsigned short* l) {
    __builtin_amdgcn_global_load_lds(
        (const __attribute__((address_space(1))) unsigned int*)g,
        (__attribute__((address_space(3))) unsigned int*)l,
        16, 0, 0);
}

// ---------------- fused setup + proj0: h1 = input @ W0 (inline cvt) + adj-pack + W2/W3 cvt + f1f2 zero ----------------
__global__ __launch_bounds__(256) void setup_proj0(
    const float* __restrict__ input, const int* __restrict__ adj,
    const float* __restrict__ W0, const float* __restrict__ W2, const float* __restrict__ W3,
    unsigned long long* __restrict__ bits, unsigned short* __restrict__ h1,
    unsigned short* __restrict__ Wbt, float* __restrict__ f1f2)
{
    const int bid = blockIdx.x;
    const int t = threadIdx.x;
    const int lane = t & 63, wave = t >> 6;
    const int g = lane >> 4, ml = lane & 15;
    __shared__ unsigned short As[32 * 264];
    __shared__ unsigned short Bs[64 * 264];

    // zero f1f2 (3 layers x 8192 floats = 24576 = 512*48)
    if (t < 48) f1f2[bid * 48 + t] = 0.f;
    // W2/W3 -> bf16 transposed (131072 elems = 512*256)
    {
        int idx = 131072 + bid * 256 + t;
        int within = idx & 65535;
        int n = within >> 8, k = within & 255;
        const float* W = ((idx >> 16) == 2) ? W2 : W3;
        Wbt[idx] = f2bf(W[k * 256 + n]);
    }
    // proj0: h1 = input @ W0 (32x64 tile, inline fp32->bf16)
    const int m0 = (bid >> 2) * 32, n0 = (bid & 3) * 64;
    {
        int ar = t >> 3, ac0 = (t & 7) * 8;
        #pragma unroll
        for (int i = 0; i < 4; ++i) {
            int col = ac0 + i * 64;
            const float* src = &input[(size_t)(m0 + ar) * 256 + col];
            ushort8v v;
            #pragma unroll
            for (int j = 0; j < 8; ++j) v[j] = f2bf(src[j]);
            *(ushort8v*)&As[ar * 264 + col] = v;
        }
        #pragma unroll 8
        for (int it = 0; it < 64; ++it) {
            int k = it * 4 + wave;
            Bs[(t & 63) * 264 + k] = f2bf(W0[k * 256 + n0 + (t & 63)]);
        }
    }
    __syncthreads();
    {
        const int wm = (wave >> 1) * 16, wn = (wave & 1) * 32;
        float4v acc[2] = {{0.f,0.f,0.f,0.f},{0.f,0.f,0.f,0.f}};
        #pragma unroll
        for (int kk = 0; kk < 256; kk += 32) {
            const int kc = kk + g * 8;
            short8 a = as_s8(*(const ushort8v*)&As[(wm + ml) * 264 + kc]);
            #pragma unroll
            for (int fn = 0; fn < 2; ++fn) {
                short8 b = as_s8(*(const ushort8v*)&Bs[(wn + fn * 16 + ml) * 264 + kc]);
                acc[fn] = __builtin_amdgcn_mfma_f32_16x16x32_bf16(a, b, acc[fn], 0, 0, 0);
            }
        }
        const int rb = wm + g * 4;
        #pragma unroll
        for (int fn = 0; fn < 2; ++fn)
            #pragma unroll
            for (int r = 0; r < 4; ++r)
                h1[(size_t)(m0 + rb + r) * 256 + n0 + wn + fn * 16 + ml] = f2bf(acc[fn][r]);
    }
    // adj-pack: 8 rows/block (wave w -> rows bid*8 + w*2 + {0,1})
    {
        #pragma unroll 1
        for (int rr = 0; rr < 2; ++rr) {
            int row = bid * 8 + wave * 2 + rr;
            const int* arow = adj + (size_t)row * NN;
            #pragma unroll 8
            for (int seg = 0; seg < 64; ++seg) {
                unsigned long long m = __ballot(arow[seg * 64 + lane] > 0);
                if (lane == 0) bits[(size_t)row * WPR + seg] = m;
            }
        }
    }
}

// ---------------- proj1: Whbt (transposed bf16) + f1f2 layer0, inline W1 cvt ----------------
__global__ __launch_bounds__(256) void proj1(
    const unsigned short* __restrict__ h1, const float* __restrict__ W1,
    const float* __restrict__ a1v, float* __restrict__ f1f2,
    unsigned short* __restrict__ Whbt)
{
    const int bid = blockIdx.x;
    const int t = threadIdx.x;
    const int lane = t & 63, wave = t >> 6;
    const int g = lane >> 4, ml = lane & 15;
    __shared__ unsigned short As[32 * 264];
    __shared__ unsigned short Bs[64 * 264];
    const int m0 = (bid >> 2) * 32, n0 = (bid & 3) * 64;
    {
        int ar = t >> 3, ac0 = (t & 7) * 8;
        #pragma unroll
        for (int i = 0; i < 4; ++i) {
            int col = ac0 + i * 64;
            *(ushort8v*)&As[ar * 264 + col] = *(const ushort8v*)&h1[(size_t)(m0 + ar) * 256 + col];
        }
        #pragma unroll 8
        for (int it = 0; it < 64; ++it) {
            int k = it * 4 + wave;
            Bs[(t & 63) * 264 + k] = f2bf(W1[k * 256 + n0 + (t & 63)]);
        }
    }
    __syncthreads();
    const int wm = (wave >> 1) * 16, wn = (wave & 1) * 32;
    float4v acc[2] = {{0.f,0.f,0.f,0.f},{0.f,0.f,0.f,0.f}};
    #pragma unroll
    for (int kk = 0; kk < 256; kk += 32) {
        const int kc = kk + g * 8;
        short8 a = as_s8(*(const ushort8v*)&As[(wm + ml) * 264 + kc]);
        #pragma unroll
        for (int fn = 0; fn < 2; ++fn) {
            short8 b = as_s8(*(const ushort8v*)&Bs[(wn + fn * 16 + ml) * 264 + kc]);
            acc[fn] = __builtin_amdgcn_mfma_f32_16x16x32_bf16(a, b, acc[fn], 0, 0, 0);
        }
    }
    const int rb = wm + g * 4;
    {
        float a1c[2], a2c[2];
        #pragma unroll
        for (int fn = 0; fn < 2; ++fn) {
            a1c[fn] = a1v[n0 + wn + fn * 16 + ml];
            a2c[fn] = a1v[256 + n0 + wn + fn * 16 + ml];
        }
        #pragma unroll
        for (int r = 0; r < 4; ++r) {
            float s1 = acc[0][r] * a1c[0] + acc[1][r] * a1c[1];
            float s2 = acc[0][r] * a2c[0] + acc[1][r] * a2c[1];
            #pragma unroll
            for (int off = 1; off < 16; off <<= 1) {
                s1 += __shfl_xor(s1, off, 64);
                s2 += __shfl_xor(s2, off, 64);
            }
            if (ml == 0) {
                int row = m0 + rb + r;
                atomicAdd(&f1f2[row], s1);
                atomicAdd(&f1f2[4096 + row], s2);
            }
        }
    }
    {
        unsigned short* T = As;
        __syncthreads();
        #pragma unroll
        for (int fn = 0; fn < 2; ++fn)
            #pragma unroll
            for (int r = 0; r < 4; ++r)
                T[(wn + fn * 16 + ml) * 40 + rb + r] = f2bf(acc[fn][r]);
        __syncthreads();
        const int tr = t >> 2, tc = (t & 3) * 8;
        *(ushort8v*)&Whbt[(size_t)(n0 + tr) * 4096 + m0 + tc] = *(const ushort8v*)&T[tr * 40 + tc];
    }
}

// ---------------- per-row coefficients + global exp tables ----------------
__global__ __launch_bounds__(256) void rowcoef(const unsigned long long* __restrict__ bits,
                                               const float* __restrict__ f1f2,
                                               float4* __restrict__ rowco,
                                               float2* __restrict__ tab2g) {
    __shared__ float2 tl[4096];
    const int t = threadIdx.x;
    const float* f2p = f1f2 + 4096;
    #pragma unroll
    for (int i = 0; i < 16; ++i) {
        float v = f2p[i * 256 + t];
        float2 pr = make_float2(__expf(v - C1), __expf(0.01f * v - C2));
        tl[i * 256 + t] = pr;
        if (blockIdx.x == 0) tab2g[i * 256 + t] = pr;
    }
    __syncthreads();
    const int lane = t & 63, wave = t >> 6;
    for (int rr = 0; rr < 2; ++rr) {
        const int row = blockIdx.x * 8 + wave * 2 + rr;
        const unsigned long long wl = bits[(size_t)row * WPR + lane];
        const float f1r = f1f2[row];
        const float th = __expf(-f1r - C1);
        float mx = 0.f, S1 = 0.f, S2 = 0.f;
        #pragma unroll 16
        for (int b = 0; b < 64; ++b) {
            unsigned long long w = __shfl(wl, b, 64);
            bool bit = (w >> lane) & 1ULL;
            float2 v = tl[b * 64 + lane];
            float ebm = bit ? v.x : 0.f;
            mx = fmaxf(mx, ebm);
            bool cond = v.x > th;
            S1 += (bit && cond)  ? v.x : 0.f;
            S2 += (bit && !cond) ? v.y : 0.f;
        }
        #pragma unroll
        for (int off = 1; off < 64; off <<= 1) {
            mx = fmaxf(mx, __shfl_xor(mx, off, 64));
            S1 += __shfl_xor(S1, off, 64);
            S2 += __shfl_xor(S2, off, 64);
        }
        if (lane == 0) {
            float M  = C1 + __logf(mx);
            float fm_ = f1r + M;
            float m  = fm_ > 0.f ? fm_ : 0.01f * fm_;    // lrelu
            float alpha = __expf(fminf(f1r + C1 - m, 60.f));
            float gamma = __expf(fminf(0.01f * (f1r + C1) - m, 60.f));
            float inv = 1.0f / (alpha * S1 + gamma * S2);
            rowco[row] = make_float4(alpha * inv, gamma * inv, th, 0.f);
        }
    }
}

// ---------------- attention GEMM: B staged via async DMA, XOR-swizzled k-chunks ----------------
template<int NSTEPS>
__global__ __launch_bounds__(256, 3) void att_gemm(const unsigned long long* __restrict__ bits,
                                                   const float4* __restrict__ rowco,
                                                   const float* __restrict__ tab2f,
                                                   const unsigned short* __restrict__ Bt,  // Whbt [256][4096]
                                                   unsigned short* __restrict__ parth) {
    const int t = threadIdx.x;
    const int bm = blockIdx.x & 31;
    const int bn = (blockIdx.x >> 5) & 1;
    const int ks = blockIdx.x >> 6;
    const int m0 = bm * 128, n0 = bn * 128;
    const int k0 = ks * (NSTEPS * 32);
    __shared__ unsigned short Bs[2][128 * 32];   // 2 x 8 KB, unpadded (DMA layout)
    const int lane = t & 63, wave = t >> 6;
    const int g = lane >> 4, ml = lane & 15;

    const int drow = lane >> 2, dcol = ((lane & 3) ^ (lane >> 4)) * 8;
    const unsigned short* dsrc0 = Bt + (size_t)(n0 + wave * 16 + drow) * 4096 + dcol;
    const unsigned short* dsrc1 = dsrc0 + (size_t)64 * 4096;
    unsigned short* dst0 = &Bs[0][wave * 512];
    unsigned short* dst1 = &Bs[0][2048 + wave * 512];
    unsigned short* dst0b = &Bs[1][wave * 512];
    unsigned short* dst1b = &Bs[1][2048 + wave * 512];

    float pA[2], pG[2];
    unsigned long long wpre[2][NSTEPS / 2];
    #pragma unroll
    for (int fm = 0; fm < 2; ++fm) {
        int row = m0 + wave * 32 + fm * 16 + ml;
        float4 rc = rowco[row];
        pA[fm] = rc.x; pG[fm] = rc.y;
        const unsigned long long* brow = bits + (size_t)row * WPR + (k0 >> 6);
        #pragma unroll
        for (int w = 0; w < NSTEPS / 2; ++w) wpre[fm][w] = brow[w];
    }

    float4v acc[2][8];
    #pragma unroll
    for (int i = 0; i < 2; ++i)
        #pragma unroll
        for (int j = 0; j < 8; ++j) acc[i][j] = (float4v){0.f, 0.f, 0.f, 0.f};

    float4v tq0, tq1, tq2, tq3;
    {
        gl_lds16(dsrc0 + k0, dst0);
        gl_lds16(dsrc1 + k0, dst1);
        const float4v* q = (const float4v*)&tab2f[2 * (k0 + g * 8)];
        tq0 = q[0]; tq1 = q[1]; tq2 = q[2]; tq3 = q[3];
    }
    __syncthreads();

    const int rdoff = ((g ^ (ml >> 2)) & 3) * 8;

    #pragma unroll
    for (int i = 0; i < NSTEPS; ++i) {
        const int kk = k0 + i * 32;
        const int p = i & 1;
        float4v nt0, nt1, nt2, nt3;
        if (i + 1 < NSTEPS) {
            gl_lds16(dsrc0 + kk + 32, p ? dst0 : dst0b);
            gl_lds16(dsrc1 + kk + 32, p ? dst1 : dst1b);
            const float4v* q = (const float4v*)&tab2f[2 * (kk + 32 + g * 8)];
            nt0 = q[0]; nt1 = q[1]; nt2 = q[2]; nt3 = q[3];
        }
        const int sh = (i & 1) * 32 + g * 8;
        short8 afr[2];
        #pragma unroll
        for (int fm = 0; fm < 2; ++fm) {
            unsigned int wh = (unsigned int)(wpre[fm][i >> 1] >> sh);
            ushort8v af;
            #pragma unroll
            for (int jj = 0; jj < 4; ++jj) {
                float4v v = (jj == 0) ? tq0 : (jj == 1) ? tq1 : (jj == 2) ? tq2 : tq3;
                float x0 = fmaxf(pA[fm] * v[0], pG[fm] * v[1]);
                float x1 = fmaxf(pA[fm] * v[2], pG[fm] * v[3]);
                x0 = ((wh >> (2 * jj)) & 1u)     ? x0 : 0.f;
                x1 = ((wh >> (2 * jj + 1)) & 1u) ? x1 : 0.f;
                union { __hip_bfloat162 b2; unsigned int u; } cv;
                cv.b2 = __float22bfloat162_rn(make_float2(x0, x1));
                ((unsigned int*)&af)[jj] = cv.u;
            }
            afr[fm] = as_s8(af);
        }
        #pragma unroll
        for (int fn = 0; fn < 8; ++fn) {
            short8 b = as_s8(*(const ushort8v*)&Bs[p][(fn * 16 + ml) * 32 + rdoff]);
            acc[0][fn] = __builtin_amdgcn_mfma_f32_16x16x32_bf16(afr[0], b, acc[0][fn], 0, 0, 0);
            acc[1][fn] = __builtin_amdgcn_mfma_f32_16x16x32_bf16(afr[1], b, acc[1][fn], 0, 0, 0);
        }
        if (i + 1 < NSTEPS) {
            __syncthreads();
            tq0 = nt0; tq1 = nt1; tq2 = nt2; tq3 = nt3;
        }
    }

    unsigned short* pbase = parth + ((size_t)ks << 20) + (size_t)(bm * 2 + bn) * 16384;
    #pragma unroll
    for (int fm = 0; fm < 2; ++fm)
        #pragma unroll
        for (int fn = 0; fn < 8; ++fn) {
            ushort4v v4;
            #pragma unroll
            for (int r = 0; r < 4; ++r) {
                __half h = __float2half(acc[fm][fn][r]);
                v4[r] = *(unsigned short*)&h;
            }
            *(ushort4v*)&pbase[((wave * 16 + fm * 8 + fn) * 64 + lane) * 4] = v4;
        }
}

// ---------------- fused reduce(partials)+ELU -> h in LDS -> proj GEMM -> Whbt + f1f2 ----------------
template<int NS>
__global__ __launch_bounds__(256) void fused_rp(const unsigned short* __restrict__ parth,
                                                const unsigned short* __restrict__ Bt,   // Wbt [256n][256k]
                                                const float* __restrict__ av,            // attention vec [512]
                                                float* __restrict__ f1f2,
                                                unsigned short* __restrict__ Cbt) {      // Whbt [256][4096]
    const int t = threadIdx.x;
    const int m0 = blockIdx.x * 16;
    __shared__ unsigned short hA[16 * 280];
    __shared__ unsigned short T[256 * 24];

    const int bmP = m0 >> 7;
    const int wavea = (m0 >> 5) & 3;
    const int fmP = (m0 >> 4) & 1;
    const int bn = t >> 7, fnc = (t >> 4) & 7;
    const int widx = wavea * 16 + fmP * 8 + fnc;
    const size_t cbase = (size_t)(bmP * 2 + bn) * 16384 + (size_t)widx * 256 + (t & 15) * 16;
    float s[16];
    #pragma unroll
    for (int e = 0; e < 16; ++e) s[e] = 0.f;
    #pragma unroll
    for (int sp = 0; sp < NS; ++sp) {
        const unsigned short* p = &parth[((size_t)sp << 20) + cbase];
        ushort8v v0 = *(const ushort8v*)p;
        ushort8v v1 = *(const ushort8v*)(p + 8);
        #pragma unroll
        for (int e = 0; e < 8; ++e) {
            unsigned short u0 = v0[e], u1 = v1[e];
            s[e]     += __half2float(*(__half*)&u0);
            s[8 + e] += __half2float(*(__half*)&u1);
        }
    }
    const int gq = (t & 15) >> 2;
    const int colb = bn * 128 + fnc * 16 + (t & 3) * 4;
    #pragma unroll
    for (int r = 0; r < 4; ++r) {
        ushort4v w4;
        #pragma unroll
        for (int c = 0; c < 4; ++c) {
            float x = s[c * 4 + r];
            x = x > 0.f ? x : (__expf(x) - 1.f);
            w4[c] = f2bf(x);
        }
        *(ushort4v*)&hA[(gq * 4 + r) * 280 + colb] = w4;
    }
    __syncthreads();

    const int lane = t & 63, wave = t >> 6;
    const int g = lane >> 4, ml = lane & 15;
    float4v acc[4] = {{0.f,0.f,0.f,0.f},{0.f,0.f,0.f,0.f},{0.f,0.f,0.f,0.f},{0.f,0.f,0.f,0.f}};
    #pragma unroll
    for (int kk = 0; kk < 256; kk += 32) {
        short8 a = as_s8(*(const ushort8v*)&hA[ml * 280 + kk + g * 8]);
        #pragma unroll
        for (int fn = 0; fn < 4; ++fn) {
            short8 b = as_s8(*(const ushort8v*)&Bt[(size_t)(wave * 64 + fn * 16 + ml) * 256 + kk + g * 8]);
            acc[fn] = __builtin_amdgcn_mfma_f32_16x16x32_bf16(a, b, acc[fn], 0, 0, 0);
        }
    }

    {
        float a1c[4], a2c[4];
        #pragma unroll
        for (int fn = 0; fn < 4; ++fn) {
            int col = wave * 64 + fn * 16 + ml;
            a1c[fn] = av[col];
            a2c[fn] = av[256 + col];
        }
        #pragma unroll
        for (int r = 0; r < 4; ++r) {
            float s1 = acc[0][r] * a1c[0] + acc[1][r] * a1c[1] + acc[2][r] * a1c[2] + acc[3][r] * a1c[3];
            float s2 = acc[0][r] * a2c[0] + acc[1][r] * a2c[1] + acc[2][r] * a2c[2] + acc[3][r] * a2c[3];
            #pragma unroll
            for (int off = 1; off < 16; off <<= 1) {
                s1 += __shfl_xor(s1, off, 64);
                s2 += __shfl_xor(s2, off, 64);
            }
            if (ml == 0) {
                int row = m0 + g * 4 + r;
                atomicAdd(&f1f2[row], s1);
                atomicAdd(&f1f2[4096 + row], s2);
            }
        }
    }

    #pragma unroll
    for (int fn = 0; fn < 4; ++fn) {
        int nl = wave * 64 + fn * 16 + ml;
        ushort4v v4;
        #pragma unroll
        for (int r = 0; r < 4; ++r) v4[r] = f2bf(acc[fn][r]);
        *(ushort4v*)&T[nl * 24 + g * 4] = v4;
    }
    __syncthreads();
    {
        const int tn = t >> 1, half = t & 1;
        #pragma unroll
        for (int pass = 0; pass < 2; ++pass) {
            int n = pass * 128 + tn;
            *(ushort8v*)&Cbt[(size_t)n * 4096 + m0 + half * 8] = *(const ushort8v*)&T[n * 24 + half * 8];
        }
    }
}

// ---------------- final reduce: partials -> ELU -> fp32 out ----------------
template<int NS>
__global__ __launch_bounds__(256) void reduce_out(const unsigned short* __restrict__ parth,
                                                  float* __restrict__ outf) {
    const int flat = (blockIdx.x * 256 + threadIdx.x) * 8;
    float s[8] = {0.f, 0.f, 0.f, 0.f, 0.f, 0.f, 0.f, 0.f};
    #pragma unroll
    for (int sp = 0; sp < NS; ++sp) {
        ushort8v v = *(const ushort8v*)&parth[((size_t)sp << 20) + flat];
        #pragma unroll
        for (int j = 0; j < 8; ++j) {
            unsigned short u = v[j];
            s[j] += __half2float(*(__half*)&u);
        }
    }
    const int tile  = flat >> 14;
    const int inner = flat & 16383;
    const int widx = inner >> 8;
    const int ls   = (inner >> 2) & 63;
    const int bm = tile >> 1, bn = tile & 1;
    const int wavea = widx >> 4, fm = (widx >> 3) & 1, fn = widx & 7;
    const int g = ls >> 4, ml = ls & 15;
    const int row0 = bm * 128 + wavea * 32 + fm * 16 + g * 4;
    const int col  = bn * 128 + fn * 16 + ml;
    #pragma unroll
    for (int r = 0; r < 4; ++r) {
        float x0 = s[r];
        float x1 = s[4 + r];
        x0 = x0 > 0.f ? x0 : (__expf(x0) - 1.f);
        x1 = x1 > 0.f ? x1 : (__expf(x1) - 1.f);
        *(float2*)&outf[(size_t)(row0 + r) * 256 + col] = make_float2(x0, x1);
    }
}

extern "C" void kernel_launch(void* const* d_in, const int* in_sizes, int n_in,
                              void* d_out, int out_size, void* d_ws, size_t ws_size,
                              hipStream_t stream) {
    const float* input = (const float*)d_in[0];
    const int*   adj   = (const int*)d_in[1];
    const float* W0    = (const float*)d_in[2];
    const float* W1    = (const float*)d_in[3];
    const float* a1    = (const float*)d_in[4];
    const float* W2    = (const float*)d_in[5];
    const float* a2    = (const float*)d_in[6];
    const float* W3    = (const float*)d_in[7];
    const float* a3    = (const float*)d_in[8];
    float* out = (float*)d_out;
    char* ws = (char*)d_ws;

    unsigned long long* bits = (unsigned long long*)(ws);                 // 2 MB
    unsigned short* h1   = (unsigned short*)(ws + (4u << 20));            // 2 MB
    unsigned short* Whbt = (unsigned short*)(ws + (6u << 20));            // 2 MB
    unsigned short* Wbt  = (unsigned short*)(ws + (8u << 20));            // 512 KB (only mats 2,3 used)
    float*  f1f2  = (float*)(ws + (9u << 20));                            // 3 layers x 32 KB
    float4* rowco = (float4*)(ws + (10u << 20));                          // 64 KB
    float2* tab2  = (float2*)(ws + (10u << 20) + (256u << 10));           // 32 KB
    unsigned short* parth = (unsigned short*)(ws + (13u << 20));          // 8 x 2 MB (fp16)
    (void)ws_size;

    float* f1f2_l[3] = { f1f2, f1f2 + 8192, f1f2 + 16384 };

    // fused setup + proj0 (adj-pack, W2/W3 cvt, f1f2 zero, h1 = input@W0)
    setup_proj0<<<512, 256, 0, stream>>>(input, adj, W0, W2, W3, bits, h1, Wbt, f1f2);

    // layer 1
    proj1<<<512, 256, 0, stream>>>(h1, W1, a1, f1f2_l[0], Whbt);
    rowcoef<<<512, 256, 0, stream>>>(bits, f1f2_l[0], rowco, tab2);
    att_gemm<16><<<512, 256, 0, stream>>>(bits, rowco, (const float*)tab2, Whbt, parth);

    // layer 2
    fused_rp<8><<<256, 256, 0, stream>>>(parth, Wbt + 2 * 65536, a2, f1f2_l[1], Whbt);
    rowcoef<<<512, 256, 0, stream>>>(bits, f1f2_l[1], rowco, tab2);
    att_gemm<16><<<512, 256, 0, stream>>>(bits, rowco, (const float*)tab2, Whbt, parth);

    // layer 3
    fused_rp<8><<<256, 256, 0, stream>>>(parth, Wbt + 3 * 65536, a3, f1f2_l[2], Whbt);
    rowcoef<<<512, 256, 0, stream>>>(bits, f1f2_l[2], rowco, tab2);
    att_gemm<16><<<512, 256, 0, stream>>>(bits, rowco, (const float*)tab2, Whbt, parth);
    reduce_out<8><<<512, 256, 0, stream>>>(parth, out);
}

// Round 6
// 288.404 us; speedup vs baseline: 5.8598x; 1.0787x over previous
//
#include <hip/hip_runtime.h>
#include <hip/hip_bf16.h>
#include <hip/hip_fp16.h>
#include <cstdint>
#include <cstddef>

#define NN 4096
#define WPR 64  // 64-bit words per adjacency row

typedef __attribute__((ext_vector_type(8))) unsigned short ushort8v;
typedef __attribute__((ext_vector_type(4))) unsigned short ushort4v;
typedef __attribute__((ext_vector_type(8))) short short8;
typedef __attribute__((ext_vector_type(4))) float float4v;

#define C1 30.0f
#define C2 0.3f    // 0.01 * C1

static __device__ __forceinline__ unsigned short f2bf(float x) {
    union { float f; unsigned int u; } v; v.f = x;
    unsigned int r = v.u + 0x7FFFu + ((v.u >> 16) & 1u);
    return (unsigned short)(r >> 16);
}

static __device__ __forceinline__ short8 as_s8(ushort8v v) {
    union { ushort8v u; short8 s; } x; x.u = v; return x.s;
}

// async 16B/lane global -> LDS DMA (wave-uniform LDS base + lane*16)
static __device__ __forceinline__ void gl_lds16(const unsigned short* g, unsigned short* l) {
    __builtin_amdgcn_global_load_lds(
        (const __attribute__((address_space(1))) unsigned int*)g,
        (__attribute__((address_space(3))) unsigned int*)l,
        16, 0, 0);
}

// ---------------- union setup kernel: DISJOINT block ranges, all independent ----------------
//  [0,4096)    : adj-pack, 1 row/block (full parallelism — R5's serial fusion starved this)
//  [4096,4864) : W1/W2/W3 -> bf16 transposed Wbt
//  [4864,4960) : f1f2 zero
//  [4960,5472) : proj0 = input @ W0 -> h1 (inline fp32->bf16; h0 tensor eliminated)
__global__ __launch_bounds__(256) void setup_p0(
    const float* __restrict__ input, const int* __restrict__ adj,
    const float* __restrict__ W0, const float* __restrict__ W1,
    const float* __restrict__ W2, const float* __restrict__ W3,
    unsigned long long* __restrict__ bits, unsigned short* __restrict__ h1,
    unsigned short* __restrict__ Wbt, float* __restrict__ f1f2)
{
    const int b = blockIdx.x;
    const int t = threadIdx.x;
    __shared__ unsigned short As[32 * 264];
    __shared__ unsigned short Bs[64 * 264];

    if (b < 4096) {
        const int wave = t >> 6, lane = t & 63;
        const int* arow = adj + (size_t)b * NN;
        #pragma unroll
        for (int it = 0; it < NN / 256; ++it) {
            int j = it * 256 + wave * 64 + lane;
            unsigned long long m = __ballot(arow[j] > 0);
            if (lane == 0) bits[(size_t)b * WPR + (it * 4 + wave)] = m;
        }
    } else if (b < 4864) {
        int idx = (b - 4096) * 256 + t;      // 0..196607 over mats W1,W2,W3
        int mat = idx >> 16;
        int within = idx & 65535;
        int n = within >> 8, k = within & 255;
        const float* W = (mat == 0) ? W1 : (mat == 1) ? W2 : W3;
        Wbt[65536 + idx] = f2bf(W[k * 256 + n]);
    } else if (b < 4960) {
        f1f2[(b - 4864) * 256 + t] = 0.f;
    } else {
        // proj0: h1 = input @ W0 (32x64 tile, inline conversions) — R5-verified body
        const int bid2 = b - 4960;
        const int lane = t & 63, wave = t >> 6;
        const int g = lane >> 4, ml = lane & 15;
        const int m0 = (bid2 >> 2) * 32, n0 = (bid2 & 3) * 64;
        {
            int ar = t >> 3, ac0 = (t & 7) * 8;
            #pragma unroll
            for (int i = 0; i < 4; ++i) {
                int col = ac0 + i * 64;
                const float* src = &input[(size_t)(m0 + ar) * 256 + col];
                ushort8v v;
                #pragma unroll
                for (int j = 0; j < 8; ++j) v[j] = f2bf(src[j]);
                *(ushort8v*)&As[ar * 264 + col] = v;
            }
            #pragma unroll 8
            for (int it = 0; it < 64; ++it) {
                int k = it * 4 + wave;
                Bs[(t & 63) * 264 + k] = f2bf(W0[k * 256 + n0 + (t & 63)]);
            }
        }
        __syncthreads();
        {
            const int wm = (wave >> 1) * 16, wn = (wave & 1) * 32;
            float4v acc[2] = {{0.f,0.f,0.f,0.f},{0.f,0.f,0.f,0.f}};
            #pragma unroll
            for (int kk = 0; kk < 256; kk += 32) {
                const int kc = kk + g * 8;
                short8 a = as_s8(*(const ushort8v*)&As[(wm + ml) * 264 + kc]);
                #pragma unroll
                for (int fn = 0; fn < 2; ++fn) {
                    short8 bfr = as_s8(*(const ushort8v*)&Bs[(wn + fn * 16 + ml) * 264 + kc]);
                    acc[fn] = __builtin_amdgcn_mfma_f32_16x16x32_bf16(a, bfr, acc[fn], 0, 0, 0);
                }
            }
            const int rb = wm + g * 4;
            #pragma unroll
            for (int fn = 0; fn < 2; ++fn)
                #pragma unroll
                for (int r = 0; r < 4; ++r)
                    h1[(size_t)(m0 + rb + r) * 256 + n0 + wn + fn * 16 + ml] = f2bf(acc[fn][r]);
        }
    }
}

// ---------------- projection GEMM (layer 1): 32x64 tiles, grid 512 ----------------
__global__ __launch_bounds__(256) void proj_gemm(const unsigned short* __restrict__ A,
                                                 const unsigned short* __restrict__ Bt,
                                                 const float* __restrict__ av,
                                                 float* __restrict__ f1f2,
                                                 unsigned short* __restrict__ Cbt) {
    const int t = threadIdx.x;
    const int bm = blockIdx.x >> 2, bn = blockIdx.x & 3;
    const int m0 = bm * 32, n0 = bn * 64;
    __shared__ unsigned short As[32 * 264];
    __shared__ unsigned short Bs[64 * 264];
    const int lane = t & 63, wave = t >> 6;
    const int wm = (wave >> 1) * 16, wn = (wave & 1) * 32;
    const int g = lane >> 4, ml = lane & 15;
    {
        int ar = t >> 3, ac0 = (t & 7) * 8;
        #pragma unroll
        for (int i = 0; i < 4; ++i) {
            int col = ac0 + i * 64;
            *(ushort8v*)&As[ar * 264 + col] = *(const ushort8v*)&A[(size_t)(m0 + ar) * 256 + col];
        }
        int br = t >> 2, bc0 = (t & 3) * 8;
        #pragma unroll
        for (int i = 0; i < 8; ++i) {
            int col = bc0 + i * 32;
            *(ushort8v*)&Bs[br * 264 + col] = *(const ushort8v*)&Bt[(size_t)(n0 + br) * 256 + col];
        }
    }
    __syncthreads();
    float4v acc[2] = {{0.f,0.f,0.f,0.f},{0.f,0.f,0.f,0.f}};
    #pragma unroll
    for (int kk = 0; kk < 256; kk += 32) {
        const int kc = kk + g * 8;
        short8 a = as_s8(*(const ushort8v*)&As[(wm + ml) * 264 + kc]);
        #pragma unroll
        for (int fn = 0; fn < 2; ++fn) {
            short8 b = as_s8(*(const ushort8v*)&Bs[(wn + fn * 16 + ml) * 264 + kc]);
            acc[fn] = __builtin_amdgcn_mfma_f32_16x16x32_bf16(a, b, acc[fn], 0, 0, 0);
        }
    }

    const int rb = wm + g * 4;
    {
        float a1c[2], a2c[2];
        #pragma unroll
        for (int fn = 0; fn < 2; ++fn) {
            a1c[fn] = av[n0 + wn + fn * 16 + ml];
            a2c[fn] = av[256 + n0 + wn + fn * 16 + ml];
        }
        #pragma unroll
        for (int r = 0; r < 4; ++r) {
            float s1 = acc[0][r] * a1c[0] + acc[1][r] * a1c[1];
            float s2 = acc[0][r] * a2c[0] + acc[1][r] * a2c[1];
            #pragma unroll
            for (int off = 1; off < 16; off <<= 1) {
                s1 += __shfl_xor(s1, off, 64);
                s2 += __shfl_xor(s2, off, 64);
            }
            if (ml == 0) {
                int row = m0 + rb + r;
                atomicAdd(&f1f2[row], s1);
                atomicAdd(&f1f2[4096 + row], s2);
            }
        }
    }

    {
        unsigned short* T = As;
        __syncthreads();
        #pragma unroll
        for (int fn = 0; fn < 2; ++fn)
            #pragma unroll
            for (int r = 0; r < 4; ++r)
                T[(wn + fn * 16 + ml) * 40 + rb + r] = f2bf(acc[fn][r]);
        __syncthreads();
        const int tr = t >> 2, tc = (t & 3) * 8;
        *(ushort8v*)&Cbt[(size_t)(n0 + tr) * 4096 + m0 + tc] = *(const ushort8v*)&T[tr * 40 + tc];
    }
}

// ---------------- per-row coefficients + global exp tables ----------------
__global__ __launch_bounds__(256) void rowcoef(const unsigned long long* __restrict__ bits,
                                               const float* __restrict__ f1f2,
                                               float4* __restrict__ rowco,
                                               float2* __restrict__ tab2g) {
    __shared__ float2 tl[4096];
    const int t = threadIdx.x;
    const float* f2p = f1f2 + 4096;
    #pragma unroll
    for (int i = 0; i < 16; ++i) {
        float v = f2p[i * 256 + t];
        float2 pr = make_float2(__expf(v - C1), __expf(0.01f * v - C2));
        tl[i * 256 + t] = pr;
        if (blockIdx.x == 0) tab2g[i * 256 + t] = pr;
    }
    __syncthreads();
    const int lane = t & 63, wave = t >> 6;
    for (int rr = 0; rr < 2; ++rr) {
        const int row = blockIdx.x * 8 + wave * 2 + rr;
        const unsigned long long wl = bits[(size_t)row * WPR + lane];
        const float f1r = f1f2[row];
        const float th = __expf(-f1r - C1);
        float mx = 0.f, S1 = 0.f, S2 = 0.f;
        #pragma unroll 16
        for (int b = 0; b < 64; ++b) {
            unsigned long long w = __shfl(wl, b, 64);
            bool bit = (w >> lane) & 1ULL;
            float2 v = tl[b * 64 + lane];
            float ebm = bit ? v.x : 0.f;
            mx = fmaxf(mx, ebm);
            bool cond = v.x > th;
            S1 += (bit && cond)  ? v.x : 0.f;
            S2 += (bit && !cond) ? v.y : 0.f;
        }
        #pragma unroll
        for (int off = 1; off < 64; off <<= 1) {
            mx = fmaxf(mx, __shfl_xor(mx, off, 64));
            S1 += __shfl_xor(S1, off, 64);
            S2 += __shfl_xor(S2, off, 64);
        }
        if (lane == 0) {
            float M  = C1 + __logf(mx);
            float fm_ = f1r + M;
            float m  = fm_ > 0.f ? fm_ : 0.01f * fm_;    // lrelu
            float alpha = __expf(fminf(f1r + C1 - m, 60.f));
            float gamma = __expf(fminf(0.01f * (f1r + C1) - m, 60.f));
            float inv = 1.0f / (alpha * S1 + gamma * S2);
            rowco[row] = make_float4(alpha * inv, gamma * inv, th, 0.f);
        }
    }
}

// ---------------- attention GEMM: B staged via async DMA, XOR-swizzled k-chunks ----------------
template<int NSTEPS>
__global__ __launch_bounds__(256, 3) void att_gemm(const unsigned long long* __restrict__ bits,
                                                   const float4* __restrict__ rowco,
                                                   const float* __restrict__ tab2f,
                                                   const unsigned short* __restrict__ Bt,  // Whbt [256][4096]
                                                   unsigned short* __restrict__ parth) {
    const int t = threadIdx.x;
    const int bm = blockIdx.x & 31;
    const int bn = (blockIdx.x >> 5) & 1;
    const int ks = blockIdx.x >> 6;
    const int m0 = bm * 128, n0 = bn * 128;
    const int k0 = ks * (NSTEPS * 32);
    __shared__ unsigned short Bs[2][128 * 32];   // 2 x 8 KB, unpadded (DMA layout)
    const int lane = t & 63, wave = t >> 6;
    const int g = lane >> 4, ml = lane & 15;

    const int drow = lane >> 2, dcol = ((lane & 3) ^ (lane >> 4)) * 8;
    const unsigned short* dsrc0 = Bt + (size_t)(n0 + wave * 16 + drow) * 4096 + dcol;
    const unsigned short* dsrc1 = dsrc0 + (size_t)64 * 4096;
    unsigned short* dst0 = &Bs[0][wave * 512];
    unsigned short* dst1 = &Bs[0][2048 + wave * 512];
    unsigned short* dst0b = &Bs[1][wave * 512];
    unsigned short* dst1b = &Bs[1][2048 + wave * 512];

    float pA[2], pG[2];
    unsigned long long wpre[2][NSTEPS / 2];
    #pragma unroll
    for (int fm = 0; fm < 2; ++fm) {
        int row = m0 + wave * 32 + fm * 16 + ml;
        float4 rc = rowco[row];
        pA[fm] = rc.x; pG[fm] = rc.y;
        const unsigned long long* brow = bits + (size_t)row * WPR + (k0 >> 6);
        #pragma unroll
        for (int w = 0; w < NSTEPS / 2; ++w) wpre[fm][w] = brow[w];
    }

    float4v acc[2][8];
    #pragma unroll
    for (int i = 0; i < 2; ++i)
        #pragma unroll
        for (int j = 0; j < 8; ++j) acc[i][j] = (float4v){0.f, 0.f, 0.f, 0.f};

    float4v tq0, tq1, tq2, tq3;
    {
        gl_lds16(dsrc0 + k0, dst0);
        gl_lds16(dsrc1 + k0, dst1);
        const float4v* q = (const float4v*)&tab2f[2 * (k0 + g * 8)];
        tq0 = q[0]; tq1 = q[1]; tq2 = q[2]; tq3 = q[3];
    }
    __syncthreads();

    const int rdoff = ((g ^ (ml >> 2)) & 3) * 8;

    #pragma unroll
    for (int i = 0; i < NSTEPS; ++i) {
        const int kk = k0 + i * 32;
        const int p = i & 1;
        float4v nt0, nt1, nt2, nt3;
        if (i + 1 < NSTEPS) {
            gl_lds16(dsrc0 + kk + 32, p ? dst0 : dst0b);
            gl_lds16(dsrc1 + kk + 32, p ? dst1 : dst1b);
            const float4v* q = (const float4v*)&tab2f[2 * (kk + 32 + g * 8)];
            nt0 = q[0]; nt1 = q[1]; nt2 = q[2]; nt3 = q[3];
        }
        const int sh = (i & 1) * 32 + g * 8;
        short8 afr[2];
        #pragma unroll
        for (int fm = 0; fm < 2; ++fm) {
            unsigned int wh = (unsigned int)(wpre[fm][i >> 1] >> sh);
            ushort8v af;
            #pragma unroll
            for (int jj = 0; jj < 4; ++jj) {
                float4v v = (jj == 0) ? tq0 : (jj == 1) ? tq1 : (jj == 2) ? tq2 : tq3;
                float x0 = fmaxf(pA[fm] * v[0], pG[fm] * v[1]);
                float x1 = fmaxf(pA[fm] * v[2], pG[fm] * v[3]);
                x0 = ((wh >> (2 * jj)) & 1u)     ? x0 : 0.f;
                x1 = ((wh >> (2 * jj + 1)) & 1u) ? x1 : 0.f;
                union { __hip_bfloat162 b2; unsigned int u; } cv;
                cv.b2 = __float22bfloat162_rn(make_float2(x0, x1));
                ((unsigned int*)&af)[jj] = cv.u;
            }
            afr[fm] = as_s8(af);
        }
        #pragma unroll
        for (int fn = 0; fn < 8; ++fn) {
            short8 b = as_s8(*(const ushort8v*)&Bs[p][(fn * 16 + ml) * 32 + rdoff]);
            acc[0][fn] = __builtin_amdgcn_mfma_f32_16x16x32_bf16(afr[0], b, acc[0][fn], 0, 0, 0);
            acc[1][fn] = __builtin_amdgcn_mfma_f32_16x16x32_bf16(afr[1], b, acc[1][fn], 0, 0, 0);
        }
        if (i + 1 < NSTEPS) {
            __syncthreads();
            tq0 = nt0; tq1 = nt1; tq2 = nt2; tq3 = nt3;
        }
    }

    unsigned short* pbase = parth + ((size_t)ks << 20) + (size_t)(bm * 2 + bn) * 16384;
    #pragma unroll
    for (int fm = 0; fm < 2; ++fm)
        #pragma unroll
        for (int fn = 0; fn < 8; ++fn) {
            ushort4v v4;
            #pragma unroll
            for (int r = 0; r < 4; ++r) {
                __half h = __float2half(acc[fm][fn][r]);
                v4[r] = *(unsigned short*)&h;
            }
            *(ushort4v*)&pbase[((wave * 16 + fm * 8 + fn) * 64 + lane) * 4] = v4;
        }
}

// ---------------- fused reduce(partials)+ELU -> h in LDS -> proj GEMM -> Whbt + f1f2 ----------------
template<int NS>
__global__ __launch_bounds__(256) void fused_rp(const unsigned short* __restrict__ parth,
                                                const unsigned short* __restrict__ Bt,   // Wbt [256n][256k]
                                                const float* __restrict__ av,            // attention vec [512]
                                                float* __restrict__ f1f2,
                                                unsigned short* __restrict__ Cbt) {      // Whbt [256][4096]
    const int t = threadIdx.x;
    const int m0 = blockIdx.x * 16;
    __shared__ unsigned short hA[16 * 280];
    __shared__ unsigned short T[256 * 24];

    const int bmP = m0 >> 7;
    const int wavea = (m0 >> 5) & 3;
    const int fmP = (m0 >> 4) & 1;
    const int bn = t >> 7, fnc = (t >> 4) & 7;
    const int widx = wavea * 16 + fmP * 8 + fnc;
    const size_t cbase = (size_t)(bmP * 2 + bn) * 16384 + (size_t)widx * 256 + (t & 15) * 16;
    float s[16];
    #pragma unroll
    for (int e = 0; e < 16; ++e) s[e] = 0.f;
    #pragma unroll
    for (int sp = 0; sp < NS; ++sp) {
        const unsigned short* p = &parth[((size_t)sp << 20) + cbase];
        ushort8v v0 = *(const ushort8v*)p;
        ushort8v v1 = *(const ushort8v*)(p + 8);
        #pragma unroll
        for (int e = 0; e < 8; ++e) {
            unsigned short u0 = v0[e], u1 = v1[e];
            s[e]     += __half2float(*(__half*)&u0);
            s[8 + e] += __half2float(*(__half*)&u1);
        }
    }
    const int gq = (t & 15) >> 2;
    const int colb = bn * 128 + fnc * 16 + (t & 3) * 4;
    #pragma unroll
    for (int r = 0; r < 4; ++r) {
        ushort4v w4;
        #pragma unroll
        for (int c = 0; c < 4; ++c) {
            float x = s[c * 4 + r];
            x = x > 0.f ? x : (__expf(x) - 1.f);
            w4[c] = f2bf(x);
        }
        *(ushort4v*)&hA[(gq * 4 + r) * 280 + colb] = w4;
    }
    __syncthreads();

    const int lane = t & 63, wave = t >> 6;
    const int g = lane >> 4, ml = lane & 15;
    float4v acc[4] = {{0.f,0.f,0.f,0.f},{0.f,0.f,0.f,0.f},{0.f,0.f,0.f,0.f},{0.f,0.f,0.f,0.f}};
    #pragma unroll
    for (int kk = 0; kk < 256; kk += 32) {
        short8 a = as_s8(*(const ushort8v*)&hA[ml * 280 + kk + g * 8]);
        #pragma unroll
        for (int fn = 0; fn < 4; ++fn) {
            short8 b = as_s8(*(const ushort8v*)&Bt[(size_t)(wave * 64 + fn * 16 + ml) * 256 + kk + g * 8]);
            acc[fn] = __builtin_amdgcn_mfma_f32_16x16x32_bf16(a, b, acc[fn], 0, 0, 0);
        }
    }

    {
        float a1c[4], a2c[4];
        #pragma unroll
        for (int fn = 0; fn < 4; ++fn) {
            int col = wave * 64 + fn * 16 + ml;
            a1c[fn] = av[col];
            a2c[fn] = av[256 + col];
        }
        #pragma unroll
        for (int r = 0; r < 4; ++r) {
            float s1 = acc[0][r] * a1c[0] + acc[1][r] * a1c[1] + acc[2][r] * a1c[2] + acc[3][r] * a1c[3];
            float s2 = acc[0][r] * a2c[0] + acc[1][r] * a2c[1] + acc[2][r] * a2c[2] + acc[3][r] * a2c[3];
            #pragma unroll
            for (int off = 1; off < 16; off <<= 1) {
                s1 += __shfl_xor(s1, off, 64);
                s2 += __shfl_xor(s2, off, 64);
            }
            if (ml == 0) {
                int row = m0 + g * 4 + r;
                atomicAdd(&f1f2[row], s1);
                atomicAdd(&f1f2[4096 + row], s2);
            }
        }
    }

    #pragma unroll
    for (int fn = 0; fn < 4; ++fn) {
        int nl = wave * 64 + fn * 16 + ml;
        ushort4v v4;
        #pragma unroll
        for (int r = 0; r < 4; ++r) v4[r] = f2bf(acc[fn][r]);
        *(ushort4v*)&T[nl * 24 + g * 4] = v4;
    }
    __syncthreads();
    {
        const int tn = t >> 1, half = t & 1;
        #pragma unroll
        for (int pass = 0; pass < 2; ++pass) {
            int n = pass * 128 + tn;
            *(ushort8v*)&Cbt[(size_t)n * 4096 + m0 + half * 8] = *(const ushort8v*)&T[n * 24 + half * 8];
        }
    }
}

// ---------------- final reduce: partials -> ELU -> fp32 out ----------------
template<int NS>
__global__ __launch_bounds__(256) void reduce_out(const unsigned short* __restrict__ parth,
                                                  float* __restrict__ outf) {
    const int flat = (blockIdx.x * 256 + threadIdx.x) * 8;
    float s[8] = {0.f, 0.f, 0.f, 0.f, 0.f, 0.f, 0.f, 0.f};
    #pragma unroll
    for (int sp = 0; sp < NS; ++sp) {
        ushort8v v = *(const ushort8v*)&parth[((size_t)sp << 20) + flat];
        #pragma unroll
        for (int j = 0; j < 8; ++j) {
            unsigned short u = v[j];
            s[j] += __half2float(*(__half*)&u);
        }
    }
    const int tile  = flat >> 14;
    const int inner = flat & 16383;
    const int widx = inner >> 8;
    const int ls   = (inner >> 2) & 63;
    const int bm = tile >> 1, bn = tile & 1;
    const int wavea = widx >> 4, fm = (widx >> 3) & 1, fn = widx & 7;
    const int g = ls >> 4, ml = ls & 15;
    const int row0 = bm * 128 + wavea * 32 + fm * 16 + g * 4;
    const int col  = bn * 128 + fn * 16 + ml;
    #pragma unroll
    for (int r = 0; r < 4; ++r) {
        float x0 = s[r];
        float x1 = s[4 + r];
        x0 = x0 > 0.f ? x0 : (__expf(x0) - 1.f);
        x1 = x1 > 0.f ? x1 : (__expf(x1) - 1.f);
        *(float2*)&outf[(size_t)(row0 + r) * 256 + col] = make_float2(x0, x1);
    }
}

extern "C" void kernel_launch(void* const* d_in, const int* in_sizes, int n_in,
                              void* d_out, int out_size, void* d_ws, size_t ws_size,
                              hipStream_t stream) {
    const float* input = (const float*)d_in[0];
    const int*   adj   = (const int*)d_in[1];
    const float* W0    = (const float*)d_in[2];
    const float* W1    = (const float*)d_in[3];
    const float* a1    = (const float*)d_in[4];
    const float* W2    = (const float*)d_in[5];
    const float* a2    = (const float*)d_in[6];
    const float* W3    = (const float*)d_in[7];
    const float* a3    = (const float*)d_in[8];
    float* out = (float*)d_out;
    char* ws = (char*)d_ws;

    unsigned long long* bits = (unsigned long long*)(ws);                 // 2 MB
    unsigned short* h1   = (unsigned short*)(ws + (4u << 20));            // 2 MB
    unsigned short* Whbt = (unsigned short*)(ws + (6u << 20));            // 2 MB
    unsigned short* Wbt  = (unsigned short*)(ws + (8u << 20));            // 512 KB (mats 1,2,3 used)
    float*  f1f2  = (float*)(ws + (9u << 20));                            // 3 layers x 32 KB
    float4* rowco = (float4*)(ws + (10u << 20));                          // 64 KB
    float2* tab2  = (float2*)(ws + (10u << 20) + (256u << 10));           // 32 KB
    unsigned short* parth = (unsigned short*)(ws + (13u << 20));          // 8 x 2 MB (fp16)
    (void)ws_size;

    float* f1f2_l[3] = { f1f2, f1f2 + 8192, f1f2 + 16384 };

    // union setup: adj-pack (4096 blks) ∥ W1-3 cvt (768) ∥ f1f2 zero (96) ∥ proj0 (512)
    setup_p0<<<5472, 256, 0, stream>>>(input, adj, W0, W1, W2, W3, bits, h1, Wbt, f1f2);

    // layer 1
    proj_gemm<<<512, 256, 0, stream>>>(h1, Wbt + 1 * 65536, a1, f1f2_l[0], Whbt);
    rowcoef<<<512, 256, 0, stream>>>(bits, f1f2_l[0], rowco, tab2);
    att_gemm<16><<<512, 256, 0, stream>>>(bits, rowco, (const float*)tab2, Whbt, parth);

    // layer 2
    fused_rp<8><<<256, 256, 0, stream>>>(parth, Wbt + 2 * 65536, a2, f1f2_l[1], Whbt);
    rowcoef<<<512, 256, 0, stream>>>(bits, f1f2_l[1], rowco, tab2);
    att_gemm<16><<<512, 256, 0, stream>>>(bits, rowco, (const float*)tab2, Whbt, parth);

    // layer 3
    fused_rp<8><<<256, 256, 0, stream>>>(parth, Wbt + 3 * 65536, a3, f1f2_l[2], Whbt);
    rowcoef<<<512, 256, 0, stream>>>(bits, f1f2_l[2], rowco, tab2);
    att_gemm<16><<<512, 256, 0, stream>>>(bits, rowco, (const float*)tab2, Whbt, parth);
    reduce_out<8><<<512, 256, 0, stream>>>(parth, out);
}

// Round 7
// 284.782 us; speedup vs baseline: 5.9343x; 1.0127x over previous
//
#include <hip/hip_runtime.h>
#include <hip/hip_bf16.h>
#include <hip/hip_fp16.h>
#include <cstdint>
#include <cstddef>

#define NN 4096
#define WPR 64  // 64-bit words per adjacency row

typedef __attribute__((ext_vector_type(8))) unsigned short ushort8v;
typedef __attribute__((ext_vector_type(4))) unsigned short ushort4v;
typedef __attribute__((ext_vector_type(8))) short short8;
typedef __attribute__((ext_vector_type(4))) float float4v;

#define C1 30.0f
#define C2 0.3f    // 0.01 * C1

static __device__ __forceinline__ unsigned short f2bf(float x) {
    union { float f; unsigned int u; } v; v.f = x;
    unsigned int r = v.u + 0x7FFFu + ((v.u >> 16) & 1u);
    return (unsigned short)(r >> 16);
}

static __device__ __forceinline__ short8 as_s8(ushort8v v) {
    union { ushort8v u; short8 s; } x; x.u = v; return x.s;
}

// async 16B/lane global -> LDS DMA (wave-uniform LDS base + lane*16)
static __device__ __forceinline__ void gl_lds16(const unsigned short* g, unsigned short* l) {
    __builtin_amdgcn_global_load_lds(
        (const __attribute__((address_space(1))) unsigned int*)g,
        (__attribute__((address_space(3))) unsigned int*)l,
        16, 0, 0);
}

// ---------------- union setup kernel: DISJOINT block ranges, ZERO LDS ----------------
// R6's 50.7KB static __shared__ capped ALL blocks (incl. 4096 adj blocks) at 3 blk/CU;
// the latency-bound adj scan needs full occupancy. proj0 now feeds MFMA straight from
// global (input fp32 contiguous 32B/thread; W0 is 256KB L2-resident) -> LDS = 0.
//  [0,4096)    : adj-pack, 1 row/block
//  [4096,4864) : W1/W2/W3 -> bf16 transposed Wbt
//  [4864,4960) : f1f2 zero
//  [4960,5472) : proj0 = input @ W0 -> h1 (inline fp32->bf16, no staging)
__global__ __launch_bounds__(256) void setup_p0(
    const float* __restrict__ input, const int* __restrict__ adj,
    const float* __restrict__ W0, const float* __restrict__ W1,
    const float* __restrict__ W2, const float* __restrict__ W3,
    unsigned long long* __restrict__ bits, unsigned short* __restrict__ h1,
    unsigned short* __restrict__ Wbt, float* __restrict__ f1f2)
{
    const int b = blockIdx.x;
    const int t = threadIdx.x;

    if (b < 4096) {
        const int wave = t >> 6, lane = t & 63;
        const int* arow = adj + (size_t)b * NN;
        #pragma unroll
        for (int it = 0; it < NN / 256; ++it) {
            int j = it * 256 + wave * 64 + lane;
            unsigned long long m = __ballot(arow[j] > 0);
            if (lane == 0) bits[(size_t)b * WPR + (it * 4 + wave)] = m;
        }
    } else if (b < 4864) {
        int idx = (b - 4096) * 256 + t;      // 0..196607 over mats W1,W2,W3
        int mat = idx >> 16;
        int within = idx & 65535;
        int n = within >> 8, k = within & 255;
        const float* W = (mat == 0) ? W1 : (mat == 1) ? W2 : W3;
        Wbt[65536 + idx] = f2bf(W[k * 256 + n]);
    } else if (b < 4960) {
        f1f2[(b - 4864) * 256 + t] = 0.f;
    } else {
        // proj0: h1 = input @ W0, 32x64 tile, fragments direct from global
        const int bid2 = b - 4960;
        const int lane = t & 63, wave = t >> 6;
        const int g = lane >> 4, ml = lane & 15;
        const int m0 = (bid2 >> 2) * 32, n0 = (bid2 & 3) * 64;
        const int wm = (wave >> 1) * 16, wn = (wave & 1) * 32;

        const float* arow = &input[(size_t)(m0 + wm + ml) * 256];
        float4v acc[2] = {{0.f,0.f,0.f,0.f},{0.f,0.f,0.f,0.f}};
        #pragma unroll
        for (int kk = 0; kk < 256; kk += 32) {
            const int kc = kk + g * 8;
            // A: 8 contiguous fp32 (two float4), inline cvt to bf16x8
            ushort8v av8;
            {
                const float4v* ap = (const float4v*)&arow[kc];
                float4v a0 = ap[0], a1 = ap[1];
                av8[0] = f2bf(a0[0]); av8[1] = f2bf(a0[1]); av8[2] = f2bf(a0[2]); av8[3] = f2bf(a0[3]);
                av8[4] = f2bf(a1[0]); av8[5] = f2bf(a1[1]); av8[6] = f2bf(a1[2]); av8[7] = f2bf(a1[3]);
            }
            short8 a = as_s8(av8);
            #pragma unroll
            for (int fn = 0; fn < 2; ++fn) {
                const int n = n0 + wn + fn * 16 + ml;
                ushort8v bv8;
                #pragma unroll
                for (int j = 0; j < 8; ++j) bv8[j] = f2bf(W0[(size_t)(kc + j) * 256 + n]);
                acc[fn] = __builtin_amdgcn_mfma_f32_16x16x32_bf16(a, as_s8(bv8), acc[fn], 0, 0, 0);
            }
        }
        const int rb = wm + g * 4;
        #pragma unroll
        for (int fn = 0; fn < 2; ++fn)
            #pragma unroll
            for (int r = 0; r < 4; ++r)
                h1[(size_t)(m0 + rb + r) * 256 + n0 + wn + fn * 16 + ml] = f2bf(acc[fn][r]);
    }
}

// ---------------- projection GEMM (layer 1): 32x64 tiles, grid 512 ----------------
__global__ __launch_bounds__(256) void proj_gemm(const unsigned short* __restrict__ A,
                                                 const unsigned short* __restrict__ Bt,
                                                 const float* __restrict__ av,
                                                 float* __restrict__ f1f2,
                                                 unsigned short* __restrict__ Cbt) {
    const int t = threadIdx.x;
    const int bm = blockIdx.x >> 2, bn = blockIdx.x & 3;
    const int m0 = bm * 32, n0 = bn * 64;
    __shared__ unsigned short As[32 * 264];
    __shared__ unsigned short Bs[64 * 264];
    const int lane = t & 63, wave = t >> 6;
    const int wm = (wave >> 1) * 16, wn = (wave & 1) * 32;
    const int g = lane >> 4, ml = lane & 15;
    {
        int ar = t >> 3, ac0 = (t & 7) * 8;
        #pragma unroll
        for (int i = 0; i < 4; ++i) {
            int col = ac0 + i * 64;
            *(ushort8v*)&As[ar * 264 + col] = *(const ushort8v*)&A[(size_t)(m0 + ar) * 256 + col];
        }
        int br = t >> 2, bc0 = (t & 3) * 8;
        #pragma unroll
        for (int i = 0; i < 8; ++i) {
            int col = bc0 + i * 32;
            *(ushort8v*)&Bs[br * 264 + col] = *(const ushort8v*)&Bt[(size_t)(n0 + br) * 256 + col];
        }
    }
    __syncthreads();
    float4v acc[2] = {{0.f,0.f,0.f,0.f},{0.f,0.f,0.f,0.f}};
    #pragma unroll
    for (int kk = 0; kk < 256; kk += 32) {
        const int kc = kk + g * 8;
        short8 a = as_s8(*(const ushort8v*)&As[(wm + ml) * 264 + kc]);
        #pragma unroll
        for (int fn = 0; fn < 2; ++fn) {
            short8 b = as_s8(*(const ushort8v*)&Bs[(wn + fn * 16 + ml) * 264 + kc]);
            acc[fn] = __builtin_amdgcn_mfma_f32_16x16x32_bf16(a, b, acc[fn], 0, 0, 0);
        }
    }

    const int rb = wm + g * 4;
    {
        float a1c[2], a2c[2];
        #pragma unroll
        for (int fn = 0; fn < 2; ++fn) {
            a1c[fn] = av[n0 + wn + fn * 16 + ml];
            a2c[fn] = av[256 + n0 + wn + fn * 16 + ml];
        }
        #pragma unroll
        for (int r = 0; r < 4; ++r) {
            float s1 = acc[0][r] * a1c[0] + acc[1][r] * a1c[1];
            float s2 = acc[0][r] * a2c[0] + acc[1][r] * a2c[1];
            #pragma unroll
            for (int off = 1; off < 16; off <<= 1) {
                s1 += __shfl_xor(s1, off, 64);
                s2 += __shfl_xor(s2, off, 64);
            }
            if (ml == 0) {
                int row = m0 + rb + r;
                atomicAdd(&f1f2[row], s1);
                atomicAdd(&f1f2[4096 + row], s2);
            }
        }
    }

    {
        unsigned short* T = As;
        __syncthreads();
        #pragma unroll
        for (int fn = 0; fn < 2; ++fn)
            #pragma unroll
            for (int r = 0; r < 4; ++r)
                T[(wn + fn * 16 + ml) * 40 + rb + r] = f2bf(acc[fn][r]);
        __syncthreads();
        const int tr = t >> 2, tc = (t & 3) * 8;
        *(ushort8v*)&Cbt[(size_t)(n0 + tr) * 4096 + m0 + tc] = *(const ushort8v*)&T[tr * 40 + tc];
    }
}

// ---------------- per-row coefficients + global exp tables ----------------
__global__ __launch_bounds__(256) void rowcoef(const unsigned long long* __restrict__ bits,
                                               const float* __restrict__ f1f2,
                                               float4* __restrict__ rowco,
                                               float2* __restrict__ tab2g) {
    __shared__ float2 tl[4096];
    const int t = threadIdx.x;
    const float* f2p = f1f2 + 4096;
    #pragma unroll
    for (int i = 0; i < 16; ++i) {
        float v = f2p[i * 256 + t];
        float2 pr = make_float2(__expf(v - C1), __expf(0.01f * v - C2));
        tl[i * 256 + t] = pr;
        if (blockIdx.x == 0) tab2g[i * 256 + t] = pr;
    }
    __syncthreads();
    const int lane = t & 63, wave = t >> 6;
    for (int rr = 0; rr < 2; ++rr) {
        const int row = blockIdx.x * 8 + wave * 2 + rr;
        const unsigned long long wl = bits[(size_t)row * WPR + lane];
        const float f1r = f1f2[row];
        const float th = __expf(-f1r - C1);
        float mx = 0.f, S1 = 0.f, S2 = 0.f;
        #pragma unroll 16
        for (int b = 0; b < 64; ++b) {
            unsigned long long w = __shfl(wl, b, 64);
            bool bit = (w >> lane) & 1ULL;
            float2 v = tl[b * 64 + lane];
            float ebm = bit ? v.x : 0.f;
            mx = fmaxf(mx, ebm);
            bool cond = v.x > th;
            S1 += (bit && cond)  ? v.x : 0.f;
            S2 += (bit && !cond) ? v.y : 0.f;
        }
        #pragma unroll
        for (int off = 1; off < 64; off <<= 1) {
            mx = fmaxf(mx, __shfl_xor(mx, off, 64));
            S1 += __shfl_xor(S1, off, 64);
            S2 += __shfl_xor(S2, off, 64);
        }
        if (lane == 0) {
            float M  = C1 + __logf(mx);
            float fm_ = f1r + M;
            float m  = fm_ > 0.f ? fm_ : 0.01f * fm_;    // lrelu
            float alpha = __expf(fminf(f1r + C1 - m, 60.f));
            float gamma = __expf(fminf(0.01f * (f1r + C1) - m, 60.f));
            float inv = 1.0f / (alpha * S1 + gamma * S2);
            rowco[row] = make_float4(alpha * inv, gamma * inv, th, 0.f);
        }
    }
}

// ---------------- attention GEMM: B staged via async DMA, XOR-swizzled k-chunks ----------------
template<int NSTEPS>
__global__ __launch_bounds__(256, 3) void att_gemm(const unsigned long long* __restrict__ bits,
                                                   const float4* __restrict__ rowco,
                                                   const float* __restrict__ tab2f,
                                                   const unsigned short* __restrict__ Bt,  // Whbt [256][4096]
                                                   unsigned short* __restrict__ parth) {
    const int t = threadIdx.x;
    const int bm = blockIdx.x & 31;
    const int bn = (blockIdx.x >> 5) & 1;
    const int ks = blockIdx.x >> 6;
    const int m0 = bm * 128, n0 = bn * 128;
    const int k0 = ks * (NSTEPS * 32);
    __shared__ unsigned short Bs[2][128 * 32];   // 2 x 8 KB, unpadded (DMA layout)
    const int lane = t & 63, wave = t >> 6;
    const int g = lane >> 4, ml = lane & 15;

    const int drow = lane >> 2, dcol = ((lane & 3) ^ (lane >> 4)) * 8;
    const unsigned short* dsrc0 = Bt + (size_t)(n0 + wave * 16 + drow) * 4096 + dcol;
    const unsigned short* dsrc1 = dsrc0 + (size_t)64 * 4096;
    unsigned short* dst0 = &Bs[0][wave * 512];
    unsigned short* dst1 = &Bs[0][2048 + wave * 512];
    unsigned short* dst0b = &Bs[1][wave * 512];
    unsigned short* dst1b = &Bs[1][2048 + wave * 512];

    float pA[2], pG[2];
    unsigned long long wpre[2][NSTEPS / 2];
    #pragma unroll
    for (int fm = 0; fm < 2; ++fm) {
        int row = m0 + wave * 32 + fm * 16 + ml;
        float4 rc = rowco[row];
        pA[fm] = rc.x; pG[fm] = rc.y;
        const unsigned long long* brow = bits + (size_t)row * WPR + (k0 >> 6);
        #pragma unroll
        for (int w = 0; w < NSTEPS / 2; ++w) wpre[fm][w] = brow[w];
    }

    float4v acc[2][8];
    #pragma unroll
    for (int i = 0; i < 2; ++i)
        #pragma unroll
        for (int j = 0; j < 8; ++j) acc[i][j] = (float4v){0.f, 0.f, 0.f, 0.f};

    float4v tq0, tq1, tq2, tq3;
    {
        gl_lds16(dsrc0 + k0, dst0);
        gl_lds16(dsrc1 + k0, dst1);
        const float4v* q = (const float4v*)&tab2f[2 * (k0 + g * 8)];
        tq0 = q[0]; tq1 = q[1]; tq2 = q[2]; tq3 = q[3];
    }
    __syncthreads();

    const int rdoff = ((g ^ (ml >> 2)) & 3) * 8;

    #pragma unroll
    for (int i = 0; i < NSTEPS; ++i) {
        const int kk = k0 + i * 32;
        const int p = i & 1;
        float4v nt0, nt1, nt2, nt3;
        if (i + 1 < NSTEPS) {
            gl_lds16(dsrc0 + kk + 32, p ? dst0 : dst0b);
            gl_lds16(dsrc1 + kk + 32, p ? dst1 : dst1b);
            const float4v* q = (const float4v*)&tab2f[2 * (kk + 32 + g * 8)];
            nt0 = q[0]; nt1 = q[1]; nt2 = q[2]; nt3 = q[3];
        }
        const int sh = (i & 1) * 32 + g * 8;
        short8 afr[2];
        #pragma unroll
        for (int fm = 0; fm < 2; ++fm) {
            unsigned int wh = (unsigned int)(wpre[fm][i >> 1] >> sh);
            ushort8v af;
            #pragma unroll
            for (int jj = 0; jj < 4; ++jj) {
                float4v v = (jj == 0) ? tq0 : (jj == 1) ? tq1 : (jj == 2) ? tq2 : tq3;
                float x0 = fmaxf(pA[fm] * v[0], pG[fm] * v[1]);
                float x1 = fmaxf(pA[fm] * v[2], pG[fm] * v[3]);
                x0 = ((wh >> (2 * jj)) & 1u)     ? x0 : 0.f;
                x1 = ((wh >> (2 * jj + 1)) & 1u) ? x1 : 0.f;
                union { __hip_bfloat162 b2; unsigned int u; } cv;
                cv.b2 = __float22bfloat162_rn(make_float2(x0, x1));
                ((unsigned int*)&af)[jj] = cv.u;
            }
            afr[fm] = as_s8(af);
        }
        #pragma unroll
        for (int fn = 0; fn < 8; ++fn) {
            short8 b = as_s8(*(const ushort8v*)&Bs[p][(fn * 16 + ml) * 32 + rdoff]);
            acc[0][fn] = __builtin_amdgcn_mfma_f32_16x16x32_bf16(afr[0], b, acc[0][fn], 0, 0, 0);
            acc[1][fn] = __builtin_amdgcn_mfma_f32_16x16x32_bf16(afr[1], b, acc[1][fn], 0, 0, 0);
        }
        if (i + 1 < NSTEPS) {
            __syncthreads();
            tq0 = nt0; tq1 = nt1; tq2 = nt2; tq3 = nt3;
        }
    }

    unsigned short* pbase = parth + ((size_t)ks << 20) + (size_t)(bm * 2 + bn) * 16384;
    #pragma unroll
    for (int fm = 0; fm < 2; ++fm)
        #pragma unroll
        for (int fn = 0; fn < 8; ++fn) {
            ushort4v v4;
            #pragma unroll
            for (int r = 0; r < 4; ++r) {
                __half h = __float2half(acc[fm][fn][r]);
                v4[r] = *(unsigned short*)&h;
            }
            *(ushort4v*)&pbase[((wave * 16 + fm * 8 + fn) * 64 + lane) * 4] = v4;
        }
}

// ---------------- fused reduce(partials)+ELU -> h in LDS -> proj GEMM -> Whbt + f1f2 ----------------
template<int NS>
__global__ __launch_bounds__(256) void fused_rp(const unsigned short* __restrict__ parth,
                                                const unsigned short* __restrict__ Bt,   // Wbt [256n][256k]
                                                const float* __restrict__ av,            // attention vec [512]
                                                float* __restrict__ f1f2,
                                                unsigned short* __restrict__ Cbt) {      // Whbt [256][4096]
    const int t = threadIdx.x;
    const int m0 = blockIdx.x * 16;
    __shared__ unsigned short hA[16 * 280];
    __shared__ unsigned short T[256 * 24];

    const int bmP = m0 >> 7;
    const int wavea = (m0 >> 5) & 3;
    const int fmP = (m0 >> 4) & 1;
    const int bn = t >> 7, fnc = (t >> 4) & 7;
    const int widx = wavea * 16 + fmP * 8 + fnc;
    const size_t cbase = (size_t)(bmP * 2 + bn) * 16384 + (size_t)widx * 256 + (t & 15) * 16;
    float s[16];
    #pragma unroll
    for (int e = 0; e < 16; ++e) s[e] = 0.f;
    #pragma unroll
    for (int sp = 0; sp < NS; ++sp) {
        const unsigned short* p = &parth[((size_t)sp << 20) + cbase];
        ushort8v v0 = *(const ushort8v*)p;
        ushort8v v1 = *(const ushort8v*)(p + 8);
        #pragma unroll
        for (int e = 0; e < 8; ++e) {
            unsigned short u0 = v0[e], u1 = v1[e];
            s[e]     += __half2float(*(__half*)&u0);
            s[8 + e] += __half2float(*(__half*)&u1);
        }
    }
    const int gq = (t & 15) >> 2;
    const int colb = bn * 128 + fnc * 16 + (t & 3) * 4;
    #pragma unroll
    for (int r = 0; r < 4; ++r) {
        ushort4v w4;
        #pragma unroll
        for (int c = 0; c < 4; ++c) {
            float x = s[c * 4 + r];
            x = x > 0.f ? x : (__expf(x) - 1.f);
            w4[c] = f2bf(x);
        }
        *(ushort4v*)&hA[(gq * 4 + r) * 280 + colb] = w4;
    }
    __syncthreads();

    const int lane = t & 63, wave = t >> 6;
    const int g = lane >> 4, ml = lane & 15;
    float4v acc[4] = {{0.f,0.f,0.f,0.f},{0.f,0.f,0.f,0.f},{0.f,0.f,0.f,0.f},{0.f,0.f,0.f,0.f}};
    #pragma unroll
    for (int kk = 0; kk < 256; kk += 32) {
        short8 a = as_s8(*(const ushort8v*)&hA[ml * 280 + kk + g * 8]);
        #pragma unroll
        for (int fn = 0; fn < 4; ++fn) {
            short8 b = as_s8(*(const ushort8v*)&Bt[(size_t)(wave * 64 + fn * 16 + ml) * 256 + kk + g * 8]);
            acc[fn] = __builtin_amdgcn_mfma_f32_16x16x32_bf16(a, b, acc[fn], 0, 0, 0);
        }
    }

    {
        float a1c[4], a2c[4];
        #pragma unroll
        for (int fn = 0; fn < 4; ++fn) {
            int col = wave * 64 + fn * 16 + ml;
            a1c[fn] = av[col];
            a2c[fn] = av[256 + col];
        }
        #pragma unroll
        for (int r = 0; r < 4; ++r) {
            float s1 = acc[0][r] * a1c[0] + acc[1][r] * a1c[1] + acc[2][r] * a1c[2] + acc[3][r] * a1c[3];
            float s2 = acc[0][r] * a2c[0] + acc[1][r] * a2c[1] + acc[2][r] * a2c[2] + acc[3][r] * a2c[3];
            #pragma unroll
            for (int off = 1; off < 16; off <<= 1) {
                s1 += __shfl_xor(s1, off, 64);
                s2 += __shfl_xor(s2, off, 64);
            }
            if (ml == 0) {
                int row = m0 + g * 4 + r;
                atomicAdd(&f1f2[row], s1);
                atomicAdd(&f1f2[4096 + row], s2);
            }
        }
    }

    #pragma unroll
    for (int fn = 0; fn < 4; ++fn) {
        int nl = wave * 64 + fn * 16 + ml;
        ushort4v v4;
        #pragma unroll
        for (int r = 0; r < 4; ++r) v4[r] = f2bf(acc[fn][r]);
        *(ushort4v*)&T[nl * 24 + g * 4] = v4;
    }
    __syncthreads();
    {
        const int tn = t >> 1, half = t & 1;
        #pragma unroll
        for (int pass = 0; pass < 2; ++pass) {
            int n = pass * 128 + tn;
            *(ushort8v*)&Cbt[(size_t)n * 4096 + m0 + half * 8] = *(const ushort8v*)&T[n * 24 + half * 8];
        }
    }
}

// ---------------- final reduce: partials -> ELU -> fp32 out ----------------
template<int NS>
__global__ __launch_bounds__(256) void reduce_out(const unsigned short* __restrict__ parth,
                                                  float* __restrict__ outf) {
    const int flat = (blockIdx.x * 256 + threadIdx.x) * 8;
    float s[8] = {0.f, 0.f, 0.f, 0.f, 0.f, 0.f, 0.f, 0.f};
    #pragma unroll
    for (int sp = 0; sp < NS; ++sp) {
        ushort8v v = *(const ushort8v*)&parth[((size_t)sp << 20) + flat];
        #pragma unroll
        for (int j = 0; j < 8; ++j) {
            unsigned short u = v[j];
            s[j] += __half2float(*(__half*)&u);
        }
    }
    const int tile  = flat >> 14;
    const int inner = flat & 16383;
    const int widx = inner >> 8;
    const int ls   = (inner >> 2) & 63;
    const int bm = tile >> 1, bn = tile & 1;
    const int wavea = widx >> 4, fm = (widx >> 3) & 1, fn = widx & 7;
    const int g = ls >> 4, ml = ls & 15;
    const int row0 = bm * 128 + wavea * 32 + fm * 16 + g * 4;
    const int col  = bn * 128 + fn * 16 + ml;
    #pragma unroll
    for (int r = 0; r < 4; ++r) {
        float x0 = s[r];
        float x1 = s[4 + r];
        x0 = x0 > 0.f ? x0 : (__expf(x0) - 1.f);
        x1 = x1 > 0.f ? x1 : (__expf(x1) - 1.f);
        *(float2*)&outf[(size_t)(row0 + r) * 256 + col] = make_float2(x0, x1);
    }
}

extern "C" void kernel_launch(void* const* d_in, const int* in_sizes, int n_in,
                              void* d_out, int out_size, void* d_ws, size_t ws_size,
                              hipStream_t stream) {
    const float* input = (const float*)d_in[0];
    const int*   adj   = (const int*)d_in[1];
    const float* W0    = (const float*)d_in[2];
    const float* W1    = (const float*)d_in[3];
    const float* a1    = (const float*)d_in[4];
    const float* W2    = (const float*)d_in[5];
    const float* a2    = (const float*)d_in[6];
    const float* W3    = (const float*)d_in[7];
    const float* a3    = (const float*)d_in[8];
    float* out = (float*)d_out;
    char* ws = (char*)d_ws;

    unsigned long long* bits = (unsigned long long*)(ws);                 // 2 MB
    unsigned short* h1   = (unsigned short*)(ws + (4u << 20));            // 2 MB
    unsigned short* Whbt = (unsigned short*)(ws + (6u << 20));            // 2 MB
    unsigned short* Wbt  = (unsigned short*)(ws + (8u << 20));            // 512 KB (mats 1,2,3 used)
    float*  f1f2  = (float*)(ws + (9u << 20));                            // 3 layers x 32 KB
    float4* rowco = (float4*)(ws + (10u << 20));                          // 64 KB
    float2* tab2  = (float2*)(ws + (10u << 20) + (256u << 10));           // 32 KB
    unsigned short* parth = (unsigned short*)(ws + (13u << 20));          // 8 x 2 MB (fp16)
    (void)ws_size;

    float* f1f2_l[3] = { f1f2, f1f2 + 8192, f1f2 + 16384 };

    // union setup (LDS-free): adj-pack (4096) ∥ W1-3 cvt (768) ∥ zero (96) ∥ proj0 (512)
    setup_p0<<<5472, 256, 0, stream>>>(input, adj, W0, W1, W2, W3, bits, h1, Wbt, f1f2);

    // layer 1
    proj_gemm<<<512, 256, 0, stream>>>(h1, Wbt + 1 * 65536, a1, f1f2_l[0], Whbt);
    rowcoef<<<512, 256, 0, stream>>>(bits, f1f2_l[0], rowco, tab2);
    att_gemm<16><<<512, 256, 0, stream>>>(bits, rowco, (const float*)tab2, Whbt, parth);

    // layer 2
    fused_rp<8><<<256, 256, 0, stream>>>(parth, Wbt + 2 * 65536, a2, f1f2_l[1], Whbt);
    rowcoef<<<512, 256, 0, stream>>>(bits, f1f2_l[1], rowco, tab2);
    att_gemm<16><<<512, 256, 0, stream>>>(bits, rowco, (const float*)tab2, Whbt, parth);

    // layer 3
    fused_rp<8><<<256, 256, 0, stream>>>(parth, Wbt + 3 * 65536, a3, f1f2_l[2], Whbt);
    rowcoef<<<512, 256, 0, stream>>>(bits, f1f2_l[2], rowco, tab2);
    att_gemm<16><<<512, 256, 0, stream>>>(bits, rowco, (const float*)tab2, Whbt, parth);
    reduce_out<8><<<512, 256, 0, stream>>>(parth, out);
}

// Round 9
// 271.044 us; speedup vs baseline: 6.2351x; 1.0507x over previous
//
#include <hip/hip_runtime.h>
#include <hip/hip_bf16.h>
#include <hip/hip_fp16.h>
#include <cstdint>
#include <cstddef>

#define NN 4096
#define WPR 64  // 64-bit words per adjacency row

typedef __attribute__((ext_vector_type(8))) unsigned short ushort8v;
typedef __attribute__((ext_vector_type(4))) unsigned short ushort4v;
typedef __attribute__((ext_vector_type(8))) short short8;
typedef __attribute__((ext_vector_type(4))) float float4v;

#define C1 30.0f
#define C2 0.3f    // 0.01 * C1

static __device__ __forceinline__ unsigned short f2bf(float x) {
    union { float f; unsigned int u; } v; v.f = x;
    unsigned int r = v.u + 0x7FFFu + ((v.u >> 16) & 1u);
    return (unsigned short)(r >> 16);
}

static __device__ __forceinline__ short8 as_s8(ushort8v v) {
    union { ushort8v u; short8 s; } x; x.u = v; return x.s;
}

// async 16B/lane global -> LDS DMA (wave-uniform LDS base + lane*16)
static __device__ __forceinline__ void gl_lds16(const unsigned short* g, unsigned short* l) {
    __builtin_amdgcn_global_load_lds(
        (const __attribute__((address_space(1))) unsigned int*)g,
        (__attribute__((address_space(3))) unsigned int*)l,
        16, 0, 0);
}

// ---------------- union setup kernel: DISJOINT block ranges, ZERO LDS ----------------
//  [0,4096)    : adj-pack, 1 row/block — ballot-free: thread t owns ints [16t,16t+16),
//                4x int4 loads -> local 16-bit mask -> ONE ushort store. Little-endian
//                aliasing makes ushort[row*256+t] land exactly at bits [16t..16t+15] of
//                the u64 words rowcoef/att consume. (R7: 16x scalar-load+ballot chain
//                was issue-rate-bound at 1.4 TB/s.)
//  [4096,4864) : W1/W2/W3 -> bf16 transposed Wbt
//  [4864,4960) : f1f2 zero
//  [4960,5472) : proj0 = input @ W0 -> h1 (inline fp32->bf16, no staging)
__global__ __launch_bounds__(256) void setup_p0(
    const float* __restrict__ input, const int* __restrict__ adj,
    const float* __restrict__ W0, const float* __restrict__ W1,
    const float* __restrict__ W2, const float* __restrict__ W3,
    unsigned long long* __restrict__ bits, unsigned short* __restrict__ h1,
    unsigned short* __restrict__ Wbt, float* __restrict__ f1f2)
{
    const int b = blockIdx.x;
    const int t = threadIdx.x;

    if (b < 4096) {
        const int* arow = adj + (size_t)b * NN + t * 16;
        unsigned int m = 0;
        #pragma unroll
        for (int i = 0; i < 4; ++i) {
            const int4 v = *(const int4*)(arow + i * 4);
            m |= (v.x > 0 ? 1u : 0u) << (i * 4 + 0);
            m |= (v.y > 0 ? 1u : 0u) << (i * 4 + 1);
            m |= (v.z > 0 ? 1u : 0u) << (i * 4 + 2);
            m |= (v.w > 0 ? 1u : 0u) << (i * 4 + 3);
        }
        ((unsigned short*)bits)[(size_t)b * 256 + t] = (unsigned short)m;
    } else if (b < 4864) {
        int idx = (b - 4096) * 256 + t;      // 0..196607 over mats W1,W2,W3
        int mat = idx >> 16;
        int within = idx & 65535;
        int n = within >> 8, k = within & 255;
        const float* W = (mat == 0) ? W1 : (mat == 1) ? W2 : W3;
        Wbt[65536 + idx] = f2bf(W[k * 256 + n]);
    } else if (b < 4960) {
        f1f2[(b - 4864) * 256 + t] = 0.f;
    } else {
        // proj0: h1 = input @ W0, 32x64 tile, fragments direct from global
        const int bid2 = b - 4960;
        const int lane = t & 63, wave = t >> 6;
        const int g = lane >> 4, ml = lane & 15;
        const int m0 = (bid2 >> 2) * 32, n0 = (bid2 & 3) * 64;
        const int wm = (wave >> 1) * 16, wn = (wave & 1) * 32;

        const float* arow = &input[(size_t)(m0 + wm + ml) * 256];
        float4v acc[2] = {{0.f,0.f,0.f,0.f},{0.f,0.f,0.f,0.f}};
        #pragma unroll
        for (int kk = 0; kk < 256; kk += 32) {
            const int kc = kk + g * 8;
            // A: 8 contiguous fp32 (two float4), inline cvt to bf16x8
            ushort8v av8;
            {
                const float4v* ap = (const float4v*)&arow[kc];
                float4v a0 = ap[0], a1 = ap[1];
                av8[0] = f2bf(a0[0]); av8[1] = f2bf(a0[1]); av8[2] = f2bf(a0[2]); av8[3] = f2bf(a0[3]);
                av8[4] = f2bf(a1[0]); av8[5] = f2bf(a1[1]); av8[6] = f2bf(a1[2]); av8[7] = f2bf(a1[3]);
            }
            short8 a = as_s8(av8);
            #pragma unroll
            for (int fn = 0; fn < 2; ++fn) {
                const int n = n0 + wn + fn * 16 + ml;
                ushort8v bv8;
                #pragma unroll
                for (int j = 0; j < 8; ++j) bv8[j] = f2bf(W0[(size_t)(kc + j) * 256 + n]);
                acc[fn] = __builtin_amdgcn_mfma_f32_16x16x32_bf16(a, as_s8(bv8), acc[fn], 0, 0, 0);
            }
        }
        const int rb = wm + g * 4;
        #pragma unroll
        for (int fn = 0; fn < 2; ++fn)
            #pragma unroll
            for (int r = 0; r < 4; ++r)
                h1[(size_t)(m0 + rb + r) * 256 + n0 + wn + fn * 16 + ml] = f2bf(acc[fn][r]);
    }
}

// ---------------- projection GEMM (layer 1): 32x64 tiles, grid 512 ----------------
__global__ __launch_bounds__(256) void proj_gemm(const unsigned short* __restrict__ A,
                                                 const unsigned short* __restrict__ Bt,
                                                 const float* __restrict__ av,
                                                 float* __restrict__ f1f2,
                                                 unsigned short* __restrict__ Cbt) {
    const int t = threadIdx.x;
    const int bm = blockIdx.x >> 2, bn = blockIdx.x & 3;
    const int m0 = bm * 32, n0 = bn * 64;
    __shared__ unsigned short As[32 * 264];
    __shared__ unsigned short Bs[64 * 264];
    const int lane = t & 63, wave = t >> 6;
    const int wm = (wave >> 1) * 16, wn = (wave & 1) * 32;
    const int g = lane >> 4, ml = lane & 15;
    {
        int ar = t >> 3, ac0 = (t & 7) * 8;
        #pragma unroll
        for (int i = 0; i < 4; ++i) {
            int col = ac0 + i * 64;
            *(ushort8v*)&As[ar * 264 + col] = *(const ushort8v*)&A[(size_t)(m0 + ar) * 256 + col];
        }
        int br = t >> 2, bc0 = (t & 3) * 8;
        #pragma unroll
        for (int i = 0; i < 8; ++i) {
            int col = bc0 + i * 32;
            *(ushort8v*)&Bs[br * 264 + col] = *(const ushort8v*)&Bt[(size_t)(n0 + br) * 256 + col];
        }
    }
    __syncthreads();
    float4v acc[2] = {{0.f,0.f,0.f,0.f},{0.f,0.f,0.f,0.f}};
    #pragma unroll
    for (int kk = 0; kk < 256; kk += 32) {
        const int kc = kk + g * 8;
        short8 a = as_s8(*(const ushort8v*)&As[(wm + ml) * 264 + kc]);
        #pragma unroll
        for (int fn = 0; fn < 2; ++fn) {
            short8 b = as_s8(*(const ushort8v*)&Bs[(wn + fn * 16 + ml) * 264 + kc]);
            acc[fn] = __builtin_amdgcn_mfma_f32_16x16x32_bf16(a, b, acc[fn], 0, 0, 0);
        }
    }

    const int rb = wm + g * 4;
    {
        float a1c[2], a2c[2];
        #pragma unroll
        for (int fn = 0; fn < 2; ++fn) {
            a1c[fn] = av[n0 + wn + fn * 16 + ml];
            a2c[fn] = av[256 + n0 + wn + fn * 16 + ml];
        }
        #pragma unroll
        for (int r = 0; r < 4; ++r) {
            float s1 = acc[0][r] * a1c[0] + acc[1][r] * a1c[1];
            float s2 = acc[0][r] * a2c[0] + acc[1][r] * a2c[1];
            #pragma unroll
            for (int off = 1; off < 16; off <<= 1) {
                s1 += __shfl_xor(s1, off, 64);
                s2 += __shfl_xor(s2, off, 64);
            }
            if (ml == 0) {
                int row = m0 + rb + r;
                atomicAdd(&f1f2[row], s1);
                atomicAdd(&f1f2[4096 + row], s2);
            }
        }
    }

    {
        unsigned short* T = As;
        __syncthreads();
        #pragma unroll
        for (int fn = 0; fn < 2; ++fn)
            #pragma unroll
            for (int r = 0; r < 4; ++r)
                T[(wn + fn * 16 + ml) * 40 + rb + r] = f2bf(acc[fn][r]);
        __syncthreads();
        const int tr = t >> 2, tc = (t & 3) * 8;
        *(ushort8v*)&Cbt[(size_t)(n0 + tr) * 4096 + m0 + tc] = *(const ushort8v*)&T[tr * 40 + tc];
    }
}

// ---------------- per-row coefficients + global exp tables ----------------
__global__ __launch_bounds__(256) void rowcoef(const unsigned long long* __restrict__ bits,
                                               const float* __restrict__ f1f2,
                                               float4* __restrict__ rowco,
                                               float2* __restrict__ tab2g) {
    __shared__ float2 tl[4096];
    const int t = threadIdx.x;
    const float* f2p = f1f2 + 4096;
    #pragma unroll
    for (int i = 0; i < 16; ++i) {
        float v = f2p[i * 256 + t];
        float2 pr = make_float2(__expf(v - C1), __expf(0.01f * v - C2));
        tl[i * 256 + t] = pr;
        if (blockIdx.x == 0) tab2g[i * 256 + t] = pr;
    }
    __syncthreads();
    const int lane = t & 63, wave = t >> 6;
    for (int rr = 0; rr < 2; ++rr) {
        const int row = blockIdx.x * 8 + wave * 2 + rr;
        const unsigned long long wl = bits[(size_t)row * WPR + lane];
        const float f1r = f1f2[row];
        const float th = __expf(-f1r - C1);
        float mx = 0.f, S1 = 0.f, S2 = 0.f;
        #pragma unroll 16
        for (int b = 0; b < 64; ++b) {
            unsigned long long w = __shfl(wl, b, 64);
            bool bit = (w >> lane) & 1ULL;
            float2 v = tl[b * 64 + lane];
            float ebm = bit ? v.x : 0.f;
            mx = fmaxf(mx, ebm);
            bool cond = v.x > th;
            S1 += (bit && cond)  ? v.x : 0.f;
            S2 += (bit && !cond) ? v.y : 0.f;
        }
        #pragma unroll
        for (int off = 1; off < 64; off <<= 1) {
            mx = fmaxf(mx, __shfl_xor(mx, off, 64));
            S1 += __shfl_xor(S1, off, 64);
            S2 += __shfl_xor(S2, off, 64);
        }
        if (lane == 0) {
            float M  = C1 + __logf(mx);
            float fm_ = f1r + M;
            float m  = fm_ > 0.f ? fm_ : 0.01f * fm_;    // lrelu
            float alpha = __expf(fminf(f1r + C1 - m, 60.f));
            float gamma = __expf(fminf(0.01f * (f1r + C1) - m, 60.f));
            float inv = 1.0f / (alpha * S1 + gamma * S2);
            rowco[row] = make_float4(alpha * inv, gamma * inv, th, 0.f);
        }
    }
}

// ---------------- attention GEMM: B staged via async DMA, XOR-swizzled k-chunks ----------------
template<int NSTEPS>
__global__ __launch_bounds__(256, 3) void att_gemm(const unsigned long long* __restrict__ bits,
                                                   const float4* __restrict__ rowco,
                                                   const float* __restrict__ tab2f,
                                                   const unsigned short* __restrict__ Bt,  // Whbt [256][4096]
                                                   unsigned short* __restrict__ parth) {
    const int t = threadIdx.x;
    const int bm = blockIdx.x & 31;
    const int bn = (blockIdx.x >> 5) & 1;
    const int ks = blockIdx.x >> 6;
    const int m0 = bm * 128, n0 = bn * 128;
    const int k0 = ks * (NSTEPS * 32);
    __shared__ unsigned short Bs[2][128 * 32];   // 2 x 8 KB, unpadded (DMA layout)
    const int lane = t & 63, wave = t >> 6;
    const int g = lane >> 4, ml = lane & 15;

    const int drow = lane >> 2, dcol = ((lane & 3) ^ (lane >> 4)) * 8;
    const unsigned short* dsrc0 = Bt + (size_t)(n0 + wave * 16 + drow) * 4096 + dcol;
    const unsigned short* dsrc1 = dsrc0 + (size_t)64 * 4096;
    unsigned short* dst0 = &Bs[0][wave * 512];
    unsigned short* dst1 = &Bs[0][2048 + wave * 512];
    unsigned short* dst0b = &Bs[1][wave * 512];
    unsigned short* dst1b = &Bs[1][2048 + wave * 512];

    float pA[2], pG[2];
    unsigned long long wpre[2][NSTEPS / 2];
    #pragma unroll
    for (int fm = 0; fm < 2; ++fm) {
        int row = m0 + wave * 32 + fm * 16 + ml;
        float4 rc = rowco[row];
        pA[fm] = rc.x; pG[fm] = rc.y;
        const unsigned long long* brow = bits + (size_t)row * WPR + (k0 >> 6);
        #pragma unroll
        for (int w = 0; w < NSTEPS / 2; ++w) wpre[fm][w] = brow[w];
    }

    float4v acc[2][8];
    #pragma unroll
    for (int i = 0; i < 2; ++i)
        #pragma unroll
        for (int j = 0; j < 8; ++j) acc[i][j] = (float4v){0.f, 0.f, 0.f, 0.f};

    float4v tq0, tq1, tq2, tq3;
    {
        gl_lds16(dsrc0 + k0, dst0);
        gl_lds16(dsrc1 + k0, dst1);
        const float4v* q = (const float4v*)&tab2f[2 * (k0 + g * 8)];
        tq0 = q[0]; tq1 = q[1]; tq2 = q[2]; tq3 = q[3];
    }
    __syncthreads();

    const int rdoff = ((g ^ (ml >> 2)) & 3) * 8;

    #pragma unroll
    for (int i = 0; i < NSTEPS; ++i) {
        const int kk = k0 + i * 32;
        const int p = i & 1;
        float4v nt0, nt1, nt2, nt3;
        if (i + 1 < NSTEPS) {
            gl_lds16(dsrc0 + kk + 32, p ? dst0 : dst0b);
            gl_lds16(dsrc1 + kk + 32, p ? dst1 : dst1b);
            const float4v* q = (const float4v*)&tab2f[2 * (kk + 32 + g * 8)];
            nt0 = q[0]; nt1 = q[1]; nt2 = q[2]; nt3 = q[3];
        }
        const int sh = (i & 1) * 32 + g * 8;
        short8 afr[2];
        #pragma unroll
        for (int fm = 0; fm < 2; ++fm) {
            unsigned int wh = (unsigned int)(wpre[fm][i >> 1] >> sh);
            ushort8v af;
            #pragma unroll
            for (int jj = 0; jj < 4; ++jj) {
                float4v v = (jj == 0) ? tq0 : (jj == 1) ? tq1 : (jj == 2) ? tq2 : tq3;
                float x0 = fmaxf(pA[fm] * v[0], pG[fm] * v[1]);
                float x1 = fmaxf(pA[fm] * v[2], pG[fm] * v[3]);
                x0 = ((wh >> (2 * jj)) & 1u)     ? x0 : 0.f;
                x1 = ((wh >> (2 * jj + 1)) & 1u) ? x1 : 0.f;
                union { __hip_bfloat162 b2; unsigned int u; } cv;
                cv.b2 = __float22bfloat162_rn(make_float2(x0, x1));
                ((unsigned int*)&af)[jj] = cv.u;
            }
            afr[fm] = as_s8(af);
        }
        #pragma unroll
        for (int fn = 0; fn < 8; ++fn) {
            short8 b = as_s8(*(const ushort8v*)&Bs[p][(fn * 16 + ml) * 32 + rdoff]);
            acc[0][fn] = __builtin_amdgcn_mfma_f32_16x16x32_bf16(afr[0], b, acc[0][fn], 0, 0, 0);
            acc[1][fn] = __builtin_amdgcn_mfma_f32_16x16x32_bf16(afr[1], b, acc[1][fn], 0, 0, 0);
        }
        if (i + 1 < NSTEPS) {
            __syncthreads();
            tq0 = nt0; tq1 = nt1; tq2 = nt2; tq3 = nt3;
        }
    }

    unsigned short* pbase = parth + ((size_t)ks << 20) + (size_t)(bm * 2 + bn) * 16384;
    #pragma unroll
    for (int fm = 0; fm < 2; ++fm)
        #pragma unroll
        for (int fn = 0; fn < 8; ++fn) {
            ushort4v v4;
            #pragma unroll
            for (int r = 0; r < 4; ++r) {
                __half h = __float2half(acc[fm][fn][r]);
                v4[r] = *(unsigned short*)&h;
            }
            *(ushort4v*)&pbase[((wave * 16 + fm * 8 + fn) * 64 + lane) * 4] = v4;
        }
}

// ---------------- fused reduce(partials)+ELU -> h in LDS -> proj GEMM -> Whbt + f1f2 ----------------
template<int NS>
__global__ __launch_bounds__(256) void fused_rp(const unsigned short* __restrict__ parth,
                                                const unsigned short* __restrict__ Bt,   // Wbt [256n][256k]
                                                const float* __restrict__ av,            // attention vec [512]
                                                float* __restrict__ f1f2,
                                                unsigned short* __restrict__ Cbt) {      // Whbt [256][4096]
    const int t = threadIdx.x;
    const int m0 = blockIdx.x * 16;
    __shared__ unsigned short hA[16 * 280];
    __shared__ unsigned short T[256 * 24];

    const int bmP = m0 >> 7;
    const int wavea = (m0 >> 5) & 3;
    const int fmP = (m0 >> 4) & 1;
    const int bn = t >> 7, fnc = (t >> 4) & 7;
    const int widx = wavea * 16 + fmP * 8 + fnc;
    const size_t cbase = (size_t)(bmP * 2 + bn) * 16384 + (size_t)widx * 256 + (t & 15) * 16;
    float s[16];
    #pragma unroll
    for (int e = 0; e < 16; ++e) s[e] = 0.f;
    #pragma unroll
    for (int sp = 0; sp < NS; ++sp) {
        const unsigned short* p = &parth[((size_t)sp << 20) + cbase];
        ushort8v v0 = *(const ushort8v*)p;
        ushort8v v1 = *(const ushort8v*)(p + 8);
        #pragma unroll
        for (int e = 0; e < 8; ++e) {
            unsigned short u0 = v0[e], u1 = v1[e];
            s[e]     += __half2float(*(__half*)&u0);
            s[8 + e] += __half2float(*(__half*)&u1);
        }
    }
    const int gq = (t & 15) >> 2;
    const int colb = bn * 128 + fnc * 16 + (t & 3) * 4;
    #pragma unroll
    for (int r = 0; r < 4; ++r) {
        ushort4v w4;
        #pragma unroll
        for (int c = 0; c < 4; ++c) {
            float x = s[c * 4 + r];
            x = x > 0.f ? x : (__expf(x) - 1.f);
            w4[c] = f2bf(x);
        }
        *(ushort4v*)&hA[(gq * 4 + r) * 280 + colb] = w4;
    }
    __syncthreads();

    const int lane = t & 63, wave = t >> 6;
    const int g = lane >> 4, ml = lane & 15;
    float4v acc[4] = {{0.f,0.f,0.f,0.f},{0.f,0.f,0.f,0.f},{0.f,0.f,0.f,0.f},{0.f,0.f,0.f,0.f}};
    #pragma unroll
    for (int kk = 0; kk < 256; kk += 32) {
        short8 a = as_s8(*(const ushort8v*)&hA[ml * 280 + kk + g * 8]);
        #pragma unroll
        for (int fn = 0; fn < 4; ++fn) {
            short8 b = as_s8(*(const ushort8v*)&Bt[(size_t)(wave * 64 + fn * 16 + ml) * 256 + kk + g * 8]);
            acc[fn] = __builtin_amdgcn_mfma_f32_16x16x32_bf16(a, b, acc[fn], 0, 0, 0);
        }
    }

    {
        float a1c[4], a2c[4];
        #pragma unroll
        for (int fn = 0; fn < 4; ++fn) {
            int col = wave * 64 + fn * 16 + ml;
            a1c[fn] = av[col];
            a2c[fn] = av[256 + col];
        }
        #pragma unroll
        for (int r = 0; r < 4; ++r) {
            float s1 = acc[0][r] * a1c[0] + acc[1][r] * a1c[1] + acc[2][r] * a1c[2] + acc[3][r] * a1c[3];
            float s2 = acc[0][r] * a2c[0] + acc[1][r] * a2c[1] + acc[2][r] * a2c[2] + acc[3][r] * a2c[3];
            #pragma unroll
            for (int off = 1; off < 16; off <<= 1) {
                s1 += __shfl_xor(s1, off, 64);
                s2 += __shfl_xor(s2, off, 64);
            }
            if (ml == 0) {
                int row = m0 + g * 4 + r;
                atomicAdd(&f1f2[row], s1);
                atomicAdd(&f1f2[4096 + row], s2);
            }
        }
    }

    #pragma unroll
    for (int fn = 0; fn < 4; ++fn) {
        int nl = wave * 64 + fn * 16 + ml;
        ushort4v v4;
        #pragma unroll
        for (int r = 0; r < 4; ++r) v4[r] = f2bf(acc[fn][r]);
        *(ushort4v*)&T[nl * 24 + g * 4] = v4;
    }
    __syncthreads();
    {
        const int tn = t >> 1, half = t & 1;
        #pragma unroll
        for (int pass = 0; pass < 2; ++pass) {
            int n = pass * 128 + tn;
            *(ushort8v*)&Cbt[(size_t)n * 4096 + m0 + half * 8] = *(const ushort8v*)&T[n * 24 + half * 8];
        }
    }
}

// ---------------- final reduce: partials -> ELU -> fp32 out ----------------
template<int NS>
__global__ __launch_bounds__(256) void reduce_out(const unsigned short* __restrict__ parth,
                                                  float* __restrict__ outf) {
    const int flat = (blockIdx.x * 256 + threadIdx.x) * 8;
    float s[8] = {0.f, 0.f, 0.f, 0.f, 0.f, 0.f, 0.f, 0.f};
    #pragma unroll
    for (int sp = 0; sp < NS; ++sp) {
        ushort8v v = *(const ushort8v*)&parth[((size_t)sp << 20) + flat];
        #pragma unroll
        for (int j = 0; j < 8; ++j) {
            unsigned short u = v[j];
            s[j] += __half2float(*(__half*)&u);
        }
    }
    const int tile  = flat >> 14;
    const int inner = flat & 16383;
    const int widx = inner >> 8;
    const int ls   = (inner >> 2) & 63;
    const int bm = tile >> 1, bn = tile & 1;
    const int wavea = widx >> 4, fm = (widx >> 3) & 1, fn = widx & 7;
    const int g = ls >> 4, ml = ls & 15;
    const int row0 = bm * 128 + wavea * 32 + fm * 16 + g * 4;
    const int col  = bn * 128 + fn * 16 + ml;
    #pragma unroll
    for (int r = 0; r < 4; ++r) {
        float x0 = s[r];
        float x1 = s[4 + r];
        x0 = x0 > 0.f ? x0 : (__expf(x0) - 1.f);
        x1 = x1 > 0.f ? x1 : (__expf(x1) - 1.f);
        *(float2*)&outf[(size_t)(row0 + r) * 256 + col] = make_float2(x0, x1);
    }
}

extern "C" void kernel_launch(void* const* d_in, const int* in_sizes, int n_in,
                              void* d_out, int out_size, void* d_ws, size_t ws_size,
                              hipStream_t stream) {
    const float* input = (const float*)d_in[0];
    const int*   adj   = (const int*)d_in[1];
    const float* W0    = (const float*)d_in[2];
    const float* W1    = (const float*)d_in[3];
    const float* a1    = (const float*)d_in[4];
    const float* W2    = (const float*)d_in[5];
    const float* a2    = (const float*)d_in[6];
    const float* W3    = (const float*)d_in[7];
    const float* a3    = (const float*)d_in[8];
    float* out = (float*)d_out;
    char* ws = (char*)d_ws;

    unsigned long long* bits = (unsigned long long*)(ws);                 // 2 MB
    unsigned short* h1   = (unsigned short*)(ws + (4u << 20));            // 2 MB
    unsigned short* Whbt = (unsigned short*)(ws + (6u << 20));            // 2 MB
    unsigned short* Wbt  = (unsigned short*)(ws + (8u << 20));            // 512 KB (mats 1,2,3 used)
    float*  f1f2  = (float*)(ws + (9u << 20));                            // 3 layers x 32 KB
    float4* rowco = (float4*)(ws + (10u << 20));                          // 64 KB
    float2* tab2  = (float2*)(ws + (10u << 20) + (256u << 10));           // 32 KB
    unsigned short* parth = (unsigned short*)(ws + (13u << 20));          // 8 x 2 MB (fp16)
    (void)ws_size;

    float* f1f2_l[3] = { f1f2, f1f2 + 8192, f1f2 + 16384 };

    // union setup (LDS-free, ballot-free adj): adj (4096) ∥ W1-3 cvt (768) ∥ zero (96) ∥ proj0 (512)
    setup_p0<<<5472, 256, 0, stream>>>(input, adj, W0, W1, W2, W3, bits, h1, Wbt, f1f2);

    // layer 1
    proj_gemm<<<512, 256, 0, stream>>>(h1, Wbt + 1 * 65536, a1, f1f2_l[0], Whbt);
    rowcoef<<<512, 256, 0, stream>>>(bits, f1f2_l[0], rowco, tab2);
    att_gemm<16><<<512, 256, 0, stream>>>(bits, rowco, (const float*)tab2, Whbt, parth);

    // layer 2
    fused_rp<8><<<256, 256, 0, stream>>>(parth, Wbt + 2 * 65536, a2, f1f2_l[1], Whbt);
    rowcoef<<<512, 256, 0, stream>>>(bits, f1f2_l[1], rowco, tab2);
    att_gemm<16><<<512, 256, 0, stream>>>(bits, rowco, (const float*)tab2, Whbt, parth);

    // layer 3
    fused_rp<8><<<256, 256, 0, stream>>>(parth, Wbt + 3 * 65536, a3, f1f2_l[2], Whbt);
    rowcoef<<<512, 256, 0, stream>>>(bits, f1f2_l[2], rowco, tab2);
    att_gemm<16><<<512, 256, 0, stream>>>(bits, rowco, (const float*)tab2, Whbt, parth);
    reduce_out<8><<<512, 256, 0, stream>>>(parth, out);
}

// Round 10
// 265.333 us; speedup vs baseline: 6.3693x; 1.0215x over previous
//
#include <hip/hip_runtime.h>
#include <hip/hip_bf16.h>
#include <hip/hip_fp16.h>
#include <cstdint>
#include <cstddef>

#define NN 4096
#define WPR 64  // 64-bit words per adjacency row

typedef __attribute__((ext_vector_type(8))) unsigned short ushort8v;
typedef __attribute__((ext_vector_type(4))) unsigned short ushort4v;
typedef __attribute__((ext_vector_type(8))) short short8;
typedef __attribute__((ext_vector_type(4))) float float4v;

#define C1 30.0f
#define C2 0.3f    // 0.01 * C1

static __device__ __forceinline__ unsigned short f2bf(float x) {
    union { float f; unsigned int u; } v; v.f = x;
    unsigned int r = v.u + 0x7FFFu + ((v.u >> 16) & 1u);
    return (unsigned short)(r >> 16);
}

static __device__ __forceinline__ short8 as_s8(ushort8v v) {
    union { ushort8v u; short8 s; } x; x.u = v; return x.s;
}

// async 16B/lane global -> LDS DMA (wave-uniform LDS base + lane*16)
static __device__ __forceinline__ void gl_lds16(const unsigned short* g, unsigned short* l) {
    __builtin_amdgcn_global_load_lds(
        (const __attribute__((address_space(1))) unsigned int*)g,
        (__attribute__((address_space(3))) unsigned int*)l,
        16, 0, 0);
}

// ---------------- union setup kernel: DISJOINT block ranges, ZERO LDS ----------------
//  [0,4096)    : adj-pack, 1 row/block — ballot-free ushort aliasing (R9-verified)
//  [4096,4864) : W1/W2/W3 -> bf16 transposed Wbt
//  [4864,4960) : f1f2 zero
//  [4960,5472) : proj0 = input @ W0 -> h1 (inline fp32->bf16, no staging)
__global__ __launch_bounds__(256) void setup_p0(
    const float* __restrict__ input, const int* __restrict__ adj,
    const float* __restrict__ W0, const float* __restrict__ W1,
    const float* __restrict__ W2, const float* __restrict__ W3,
    unsigned long long* __restrict__ bits, unsigned short* __restrict__ h1,
    unsigned short* __restrict__ Wbt, float* __restrict__ f1f2)
{
    const int b = blockIdx.x;
    const int t = threadIdx.x;

    if (b < 4096) {
        const int* arow = adj + (size_t)b * NN + t * 16;
        unsigned int m = 0;
        #pragma unroll
        for (int i = 0; i < 4; ++i) {
            const int4 v = *(const int4*)(arow + i * 4);
            m |= (v.x > 0 ? 1u : 0u) << (i * 4 + 0);
            m |= (v.y > 0 ? 1u : 0u) << (i * 4 + 1);
            m |= (v.z > 0 ? 1u : 0u) << (i * 4 + 2);
            m |= (v.w > 0 ? 1u : 0u) << (i * 4 + 3);
        }
        ((unsigned short*)bits)[(size_t)b * 256 + t] = (unsigned short)m;
    } else if (b < 4864) {
        int idx = (b - 4096) * 256 + t;      // 0..196607 over mats W1,W2,W3
        int mat = idx >> 16;
        int within = idx & 65535;
        int n = within >> 8, k = within & 255;
        const float* W = (mat == 0) ? W1 : (mat == 1) ? W2 : W3;
        Wbt[65536 + idx] = f2bf(W[k * 256 + n]);
    } else if (b < 4960) {
        f1f2[(b - 4864) * 256 + t] = 0.f;
    } else {
        // proj0: h1 = input @ W0, 32x64 tile, fragments direct from global
        const int bid2 = b - 4960;
        const int lane = t & 63, wave = t >> 6;
        const int g = lane >> 4, ml = lane & 15;
        const int m0 = (bid2 >> 2) * 32, n0 = (bid2 & 3) * 64;
        const int wm = (wave >> 1) * 16, wn = (wave & 1) * 32;

        const float* arow = &input[(size_t)(m0 + wm + ml) * 256];
        float4v acc[2] = {{0.f,0.f,0.f,0.f},{0.f,0.f,0.f,0.f}};
        #pragma unroll
        for (int kk = 0; kk < 256; kk += 32) {
            const int kc = kk + g * 8;
            ushort8v av8;
            {
                const float4v* ap = (const float4v*)&arow[kc];
                float4v a0 = ap[0], a1 = ap[1];
                av8[0] = f2bf(a0[0]); av8[1] = f2bf(a0[1]); av8[2] = f2bf(a0[2]); av8[3] = f2bf(a0[3]);
                av8[4] = f2bf(a1[0]); av8[5] = f2bf(a1[1]); av8[6] = f2bf(a1[2]); av8[7] = f2bf(a1[3]);
            }
            short8 a = as_s8(av8);
            #pragma unroll
            for (int fn = 0; fn < 2; ++fn) {
                const int n = n0 + wn + fn * 16 + ml;
                ushort8v bv8;
                #pragma unroll
                for (int j = 0; j < 8; ++j) bv8[j] = f2bf(W0[(size_t)(kc + j) * 256 + n]);
                acc[fn] = __builtin_amdgcn_mfma_f32_16x16x32_bf16(a, as_s8(bv8), acc[fn], 0, 0, 0);
            }
        }
        const int rb = wm + g * 4;
        #pragma unroll
        for (int fn = 0; fn < 2; ++fn)
            #pragma unroll
            for (int r = 0; r < 4; ++r)
                h1[(size_t)(m0 + rb + r) * 256 + n0 + wn + fn * 16 + ml] = f2bf(acc[fn][r]);
    }
}

// ---------------- projection GEMM (layer 1): 32x64 tiles, grid 512 ----------------
__global__ __launch_bounds__(256) void proj_gemm(const unsigned short* __restrict__ A,
                                                 const unsigned short* __restrict__ Bt,
                                                 const float* __restrict__ av,
                                                 float* __restrict__ f1f2,
                                                 unsigned short* __restrict__ Cbt) {
    const int t = threadIdx.x;
    const int bm = blockIdx.x >> 2, bn = blockIdx.x & 3;
    const int m0 = bm * 32, n0 = bn * 64;
    __shared__ unsigned short As[32 * 264];
    __shared__ unsigned short Bs[64 * 264];
    const int lane = t & 63, wave = t >> 6;
    const int wm = (wave >> 1) * 16, wn = (wave & 1) * 32;
    const int g = lane >> 4, ml = lane & 15;
    {
        int ar = t >> 3, ac0 = (t & 7) * 8;
        #pragma unroll
        for (int i = 0; i < 4; ++i) {
            int col = ac0 + i * 64;
            *(ushort8v*)&As[ar * 264 + col] = *(const ushort8v*)&A[(size_t)(m0 + ar) * 256 + col];
        }
        int br = t >> 2, bc0 = (t & 3) * 8;
        #pragma unroll
        for (int i = 0; i < 8; ++i) {
            int col = bc0 + i * 32;
            *(ushort8v*)&Bs[br * 264 + col] = *(const ushort8v*)&Bt[(size_t)(n0 + br) * 256 + col];
        }
    }
    __syncthreads();
    float4v acc[2] = {{0.f,0.f,0.f,0.f},{0.f,0.f,0.f,0.f}};
    #pragma unroll
    for (int kk = 0; kk < 256; kk += 32) {
        const int kc = kk + g * 8;
        short8 a = as_s8(*(const ushort8v*)&As[(wm + ml) * 264 + kc]);
        #pragma unroll
        for (int fn = 0; fn < 2; ++fn) {
            short8 b = as_s8(*(const ushort8v*)&Bs[(wn + fn * 16 + ml) * 264 + kc]);
            acc[fn] = __builtin_amdgcn_mfma_f32_16x16x32_bf16(a, b, acc[fn], 0, 0, 0);
        }
    }

    const int rb = wm + g * 4;
    {
        float a1c[2], a2c[2];
        #pragma unroll
        for (int fn = 0; fn < 2; ++fn) {
            a1c[fn] = av[n0 + wn + fn * 16 + ml];
            a2c[fn] = av[256 + n0 + wn + fn * 16 + ml];
        }
        #pragma unroll
        for (int r = 0; r < 4; ++r) {
            float s1 = acc[0][r] * a1c[0] + acc[1][r] * a1c[1];
            float s2 = acc[0][r] * a2c[0] + acc[1][r] * a2c[1];
            #pragma unroll
            for (int off = 1; off < 16; off <<= 1) {
                s1 += __shfl_xor(s1, off, 64);
                s2 += __shfl_xor(s2, off, 64);
            }
            if (ml == 0) {
                int row = m0 + rb + r;
                atomicAdd(&f1f2[row], s1);
                atomicAdd(&f1f2[4096 + row], s2);
            }
        }
    }

    {
        unsigned short* T = As;
        __syncthreads();
        #pragma unroll
        for (int fn = 0; fn < 2; ++fn)
            #pragma unroll
            for (int r = 0; r < 4; ++r)
                T[(wn + fn * 16 + ml) * 40 + rb + r] = f2bf(acc[fn][r]);
        __syncthreads();
        const int tr = t >> 2, tc = (t & 3) * 8;
        *(ushort8v*)&Cbt[(size_t)(n0 + tr) * 4096 + m0 + tc] = *(const ushort8v*)&T[tr * 40 + tc];
    }
}

// ---------------- per-row coefficients + global exp tables ----------------
__global__ __launch_bounds__(256) void rowcoef(const unsigned long long* __restrict__ bits,
                                               const float* __restrict__ f1f2,
                                               float4* __restrict__ rowco,
                                               float2* __restrict__ tab2g) {
    __shared__ float2 tl[4096];
    const int t = threadIdx.x;
    const float* f2p = f1f2 + 4096;
    #pragma unroll
    for (int i = 0; i < 16; ++i) {
        float v = f2p[i * 256 + t];
        float2 pr = make_float2(__expf(v - C1), __expf(0.01f * v - C2));
        tl[i * 256 + t] = pr;
        if (blockIdx.x == 0) tab2g[i * 256 + t] = pr;
    }
    __syncthreads();
    const int lane = t & 63, wave = t >> 6;
    for (int rr = 0; rr < 2; ++rr) {
        const int row = blockIdx.x * 8 + wave * 2 + rr;
        const unsigned long long wl = bits[(size_t)row * WPR + lane];
        const float f1r = f1f2[row];
        const float th = __expf(-f1r - C1);
        float mx = 0.f, S1 = 0.f, S2 = 0.f;
        #pragma unroll 16
        for (int b = 0; b < 64; ++b) {
            unsigned long long w = __shfl(wl, b, 64);
            bool bit = (w >> lane) & 1ULL;
            float2 v = tl[b * 64 + lane];
            float ebm = bit ? v.x : 0.f;
            mx = fmaxf(mx, ebm);
            bool cond = v.x > th;
            S1 += (bit && cond)  ? v.x : 0.f;
            S2 += (bit && !cond) ? v.y : 0.f;
        }
        #pragma unroll
        for (int off = 1; off < 64; off <<= 1) {
            mx = fmaxf(mx, __shfl_xor(mx, off, 64));
            S1 += __shfl_xor(S1, off, 64);
            S2 += __shfl_xor(S2, off, 64);
        }
        if (lane == 0) {
            float M  = C1 + __logf(mx);
            float fm_ = f1r + M;
            float m  = fm_ > 0.f ? fm_ : 0.01f * fm_;    // lrelu
            float alpha = __expf(fminf(f1r + C1 - m, 60.f));
            float gamma = __expf(fminf(0.01f * (f1r + C1) - m, 60.f));
            float inv = 1.0f / (alpha * S1 + gamma * S2);
            rowco[row] = make_float4(alpha * inv, gamma * inv, th, 0.f);
        }
    }
}

// ---------------- attention GEMM v14: 3-buffer DMA pipeline, counted vmcnt ----------------
// R9's 2-buffer + __syncthreads drained the SAME-STEP DMA every step (vmcnt(0) in the
// barrier) -> each of 15 steps paid the DMA round trip. Now: DMA issued 2 steps ahead
// into 3 buffers; step-end sync = asm vmcnt(6) (waits exactly DMA(i+1): newest 6 =
// DMA(i+2)x2 + tab(i+1)x4) + raw s_barrier + sched_barrier(0). Boundary step
// (i==NSTEPS-2, DMA issue stops -> counting shifts) uses one full __syncthreads.
template<int NSTEPS>
__global__ __launch_bounds__(256, 3) void att_gemm(const unsigned long long* __restrict__ bits,
                                                   const float4* __restrict__ rowco,
                                                   const float* __restrict__ tab2f,
                                                   const unsigned short* __restrict__ Bt,  // Whbt [256][4096]
                                                   unsigned short* __restrict__ parth) {
    const int t = threadIdx.x;
    const int bm = blockIdx.x & 31;
    const int bn = (blockIdx.x >> 5) & 1;
    const int ks = blockIdx.x >> 6;
    const int m0 = bm * 128, n0 = bn * 128;
    const int k0 = ks * (NSTEPS * 32);
    __shared__ unsigned short Bs[3][128 * 32];   // 3 x 8 KB triple-buffer (72 KB @ 3 blk/CU)
    const int lane = t & 63, wave = t >> 6;
    const int g = lane >> 4, ml = lane & 15;

    const int drow = lane >> 2, dcol = ((lane & 3) ^ (lane >> 4)) * 8;
    const unsigned short* dsrc0 = Bt + (size_t)(n0 + wave * 16 + drow) * 4096 + dcol;
    const unsigned short* dsrc1 = dsrc0 + (size_t)64 * 4096;

    float pA[2], pG[2];
    unsigned long long wpre[2][NSTEPS / 2];
    #pragma unroll
    for (int fm = 0; fm < 2; ++fm) {
        int row = m0 + wave * 32 + fm * 16 + ml;
        float4 rc = rowco[row];
        pA[fm] = rc.x; pG[fm] = rc.y;
        const unsigned long long* brow = bits + (size_t)row * WPR + (k0 >> 6);
        #pragma unroll
        for (int w = 0; w < NSTEPS / 2; ++w) wpre[fm][w] = brow[w];
    }

    float4v acc[2][8];
    #pragma unroll
    for (int i = 0; i < 2; ++i)
        #pragma unroll
        for (int j = 0; j < 8; ++j) acc[i][j] = (float4v){0.f, 0.f, 0.f, 0.f};

    // prologue: DMA step0->buf0, step1->buf1; tab0 -> regs; wait own step0 DMA; barrier
    float4v tq0, tq1, tq2, tq3;
    {
        gl_lds16(dsrc0 + k0, &Bs[0][wave * 512]);
        gl_lds16(dsrc1 + k0, &Bs[0][2048 + wave * 512]);
        gl_lds16(dsrc0 + k0 + 32, &Bs[1][wave * 512]);
        gl_lds16(dsrc1 + k0 + 32, &Bs[1][2048 + wave * 512]);
        const float4v* q = (const float4v*)&tab2f[2 * (k0 + g * 8)];
        tq0 = q[0]; tq1 = q[1]; tq2 = q[2]; tq3 = q[3];
    }
    asm volatile("s_waitcnt vmcnt(6)" ::: "memory");   // newest 6 = DMA(1)x2 + tab(0)x4
    __builtin_amdgcn_s_barrier();
    __builtin_amdgcn_sched_barrier(0);

    const int rdoff = ((g ^ (ml >> 2)) & 3) * 8;

    #pragma unroll
    for (int i = 0; i < NSTEPS; ++i) {
        const int kk = k0 + i * 32;
        const int p = i % 3;
        float4v nt0, nt1, nt2, nt3;
        if (i + 2 < NSTEPS) {
            const int q2 = (i + 2) % 3;
            gl_lds16(dsrc0 + kk + 64, &Bs[q2][wave * 512]);
            gl_lds16(dsrc1 + kk + 64, &Bs[q2][2048 + wave * 512]);
        }
        if (i + 1 < NSTEPS) {
            const float4v* q = (const float4v*)&tab2f[2 * (kk + 32 + g * 8)];
            nt0 = q[0]; nt1 = q[1]; nt2 = q[2]; nt3 = q[3];
        }
        // A-gen: pure reg math
        const int sh = (i & 1) * 32 + g * 8;
        short8 afr[2];
        #pragma unroll
        for (int fm = 0; fm < 2; ++fm) {
            unsigned int wh = (unsigned int)(wpre[fm][i >> 1] >> sh);
            ushort8v af;
            #pragma unroll
            for (int jj = 0; jj < 4; ++jj) {
                float4v v = (jj == 0) ? tq0 : (jj == 1) ? tq1 : (jj == 2) ? tq2 : tq3;
                float x0 = fmaxf(pA[fm] * v[0], pG[fm] * v[1]);
                float x1 = fmaxf(pA[fm] * v[2], pG[fm] * v[3]);
                x0 = ((wh >> (2 * jj)) & 1u)     ? x0 : 0.f;
                x1 = ((wh >> (2 * jj + 1)) & 1u) ? x1 : 0.f;
                union { __hip_bfloat162 b2; unsigned int u; } cv;
                cv.b2 = __float22bfloat162_rn(make_float2(x0, x1));
                ((unsigned int*)&af)[jj] = cv.u;
            }
            afr[fm] = as_s8(af);
        }
        // MFMA from LDS B (buffer p, swizzled chunk)
        #pragma unroll
        for (int fn = 0; fn < 8; ++fn) {
            short8 b = as_s8(*(const ushort8v*)&Bs[p][(fn * 16 + ml) * 32 + rdoff]);
            acc[0][fn] = __builtin_amdgcn_mfma_f32_16x16x32_bf16(afr[0], b, acc[0][fn], 0, 0, 0);
            acc[1][fn] = __builtin_amdgcn_mfma_f32_16x16x32_bf16(afr[1], b, acc[1][fn], 0, 0, 0);
        }
        if (i + 1 < NSTEPS) {
            if (i == NSTEPS - 2) {
                __syncthreads();   // boundary: DMA issue stopped, counting shifted -> full drain
            } else {
                asm volatile("s_waitcnt vmcnt(6)" ::: "memory");  // waits exactly DMA(i+1)
                __builtin_amdgcn_s_barrier();
                __builtin_amdgcn_sched_barrier(0);
            }
            tq0 = nt0; tq1 = nt1; tq2 = nt2; tq3 = nt3;
        }
    }

    // permuted coalesced fp16 epilogue
    unsigned short* pbase = parth + ((size_t)ks << 20) + (size_t)(bm * 2 + bn) * 16384;
    #pragma unroll
    for (int fm = 0; fm < 2; ++fm)
        #pragma unroll
        for (int fn = 0; fn < 8; ++fn) {
            ushort4v v4;
            #pragma unroll
            for (int r = 0; r < 4; ++r) {
                __half h = __float2half(acc[fm][fn][r]);
                v4[r] = *(unsigned short*)&h;
            }
            *(ushort4v*)&pbase[((wave * 16 + fm * 8 + fn) * 64 + lane) * 4] = v4;
        }
}

// ---------------- fused reduce(partials)+ELU -> h in LDS -> proj GEMM -> Whbt + f1f2 ----------------
template<int NS>
__global__ __launch_bounds__(256) void fused_rp(const unsigned short* __restrict__ parth,
                                                const unsigned short* __restrict__ Bt,   // Wbt [256n][256k]
                                                const float* __restrict__ av,            // attention vec [512]
                                                float* __restrict__ f1f2,
                                                unsigned short* __restrict__ Cbt) {      // Whbt [256][4096]
    const int t = threadIdx.x;
    const int m0 = blockIdx.x * 16;
    __shared__ unsigned short hA[16 * 280];
    __shared__ unsigned short T[256 * 24];

    const int bmP = m0 >> 7;
    const int wavea = (m0 >> 5) & 3;
    const int fmP = (m0 >> 4) & 1;
    const int bn = t >> 7, fnc = (t >> 4) & 7;
    const int widx = wavea * 16 + fmP * 8 + fnc;
    const size_t cbase = (size_t)(bmP * 2 + bn) * 16384 + (size_t)widx * 256 + (t & 15) * 16;
    float s[16];
    #pragma unroll
    for (int e = 0; e < 16; ++e) s[e] = 0.f;
    #pragma unroll
    for (int sp = 0; sp < NS; ++sp) {
        const unsigned short* p = &parth[((size_t)sp << 20) + cbase];
        ushort8v v0 = *(const ushort8v*)p;
        ushort8v v1 = *(const ushort8v*)(p + 8);
        #pragma unroll
        for (int e = 0; e < 8; ++e) {
            unsigned short u0 = v0[e], u1 = v1[e];
            s[e]     += __half2float(*(__half*)&u0);
            s[8 + e] += __half2float(*(__half*)&u1);
        }
    }
    const int gq = (t & 15) >> 2;
    const int colb = bn * 128 + fnc * 16 + (t & 3) * 4;
    #pragma unroll
    for (int r = 0; r < 4; ++r) {
        ushort4v w4;
        #pragma unroll
        for (int c = 0; c < 4; ++c) {
            float x = s[c * 4 + r];
            x = x > 0.f ? x : (__expf(x) - 1.f);
            w4[c] = f2bf(x);
        }
        *(ushort4v*)&hA[(gq * 4 + r) * 280 + colb] = w4;
    }
    __syncthreads();

    const int lane = t & 63, wave = t >> 6;
    const int g = lane >> 4, ml = lane & 15;
    float4v acc[4] = {{0.f,0.f,0.f,0.f},{0.f,0.f,0.f,0.f},{0.f,0.f,0.f,0.f},{0.f,0.f,0.f,0.f}};
    #pragma unroll
    for (int kk = 0; kk < 256; kk += 32) {
        short8 a = as_s8(*(const ushort8v*)&hA[ml * 280 + kk + g * 8]);
        #pragma unroll
        for (int fn = 0; fn < 4; ++fn) {
            short8 b = as_s8(*(const ushort8v*)&Bt[(size_t)(wave * 64 + fn * 16 + ml) * 256 + kk + g * 8]);
            acc[fn] = __builtin_amdgcn_mfma_f32_16x16x32_bf16(a, b, acc[fn], 0, 0, 0);
        }
    }

    {
        float a1c[4], a2c[4];
        #pragma unroll
        for (int fn = 0; fn < 4; ++fn) {
            int col = wave * 64 + fn * 16 + ml;
            a1c[fn] = av[col];
            a2c[fn] = av[256 + col];
        }
        #pragma unroll
        for (int r = 0; r < 4; ++r) {
            float s1 = acc[0][r] * a1c[0] + acc[1][r] * a1c[1] + acc[2][r] * a1c[2] + acc[3][r] * a1c[3];
            float s2 = acc[0][r] * a2c[0] + acc[1][r] * a2c[1] + acc[2][r] * a2c[2] + acc[3][r] * a2c[3];
            #pragma unroll
            for (int off = 1; off < 16; off <<= 1) {
                s1 += __shfl_xor(s1, off, 64);
                s2 += __shfl_xor(s2, off, 64);
            }
            if (ml == 0) {
                int row = m0 + g * 4 + r;
                atomicAdd(&f1f2[row], s1);
                atomicAdd(&f1f2[4096 + row], s2);
            }
        }
    }

    #pragma unroll
    for (int fn = 0; fn < 4; ++fn) {
        int nl = wave * 64 + fn * 16 + ml;
        ushort4v v4;
        #pragma unroll
        for (int r = 0; r < 4; ++r) v4[r] = f2bf(acc[fn][r]);
        *(ushort4v*)&T[nl * 24 + g * 4] = v4;
    }
    __syncthreads();
    {
        const int tn = t >> 1, half = t & 1;
        #pragma unroll
        for (int pass = 0; pass < 2; ++pass) {
            int n = pass * 128 + tn;
            *(ushort8v*)&Cbt[(size_t)n * 4096 + m0 + half * 8] = *(const ushort8v*)&T[n * 24 + half * 8];
        }
    }
}

// ---------------- final reduce: partials -> ELU -> fp32 out ----------------
template<int NS>
__global__ __launch_bounds__(256) void reduce_out(const unsigned short* __restrict__ parth,
                                                  float* __restrict__ outf) {
    const int flat = (blockIdx.x * 256 + threadIdx.x) * 8;
    float s[8] = {0.f, 0.f, 0.f, 0.f, 0.f, 0.f, 0.f, 0.f};
    #pragma unroll
    for (int sp = 0; sp < NS; ++sp) {
        ushort8v v = *(const ushort8v*)&parth[((size_t)sp << 20) + flat];
        #pragma unroll
        for (int j = 0; j < 8; ++j) {
            unsigned short u = v[j];
            s[j] += __half2float(*(__half*)&u);
        }
    }
    const int tile  = flat >> 14;
    const int inner = flat & 16383;
    const int widx = inner >> 8;
    const int ls   = (inner >> 2) & 63;
    const int bm = tile >> 1, bn = tile & 1;
    const int wavea = widx >> 4, fm = (widx >> 3) & 1, fn = widx & 7;
    const int g = ls >> 4, ml = ls & 15;
    const int row0 = bm * 128 + wavea * 32 + fm * 16 + g * 4;
    const int col  = bn * 128 + fn * 16 + ml;
    #pragma unroll
    for (int r = 0; r < 4; ++r) {
        float x0 = s[r];
        float x1 = s[4 + r];
        x0 = x0 > 0.f ? x0 : (__expf(x0) - 1.f);
        x1 = x1 > 0.f ? x1 : (__expf(x1) - 1.f);
        *(float2*)&outf[(size_t)(row0 + r) * 256 + col] = make_float2(x0, x1);
    }
}

extern "C" void kernel_launch(void* const* d_in, const int* in_sizes, int n_in,
                              void* d_out, int out_size, void* d_ws, size_t ws_size,
                              hipStream_t stream) {
    const float* input = (const float*)d_in[0];
    const int*   adj   = (const int*)d_in[1];
    const float* W0    = (const float*)d_in[2];
    const float* W1    = (const float*)d_in[3];
    const float* a1    = (const float*)d_in[4];
    const float* W2    = (const float*)d_in[5];
    const float* a2    = (const float*)d_in[6];
    const float* W3    = (const float*)d_in[7];
    const float* a3    = (const float*)d_in[8];
    float* out = (float*)d_out;
    char* ws = (char*)d_ws;

    unsigned long long* bits = (unsigned long long*)(ws);                 // 2 MB
    unsigned short* h1   = (unsigned short*)(ws + (4u << 20));            // 2 MB
    unsigned short* Whbt = (unsigned short*)(ws + (6u << 20));            // 2 MB
    unsigned short* Wbt  = (unsigned short*)(ws + (8u << 20));            // 512 KB (mats 1,2,3 used)
    float*  f1f2  = (float*)(ws + (9u << 20));                            // 3 layers x 32 KB
    float4* rowco = (float4*)(ws + (10u << 20));                          // 64 KB
    float2* tab2  = (float2*)(ws + (10u << 20) + (256u << 10));           // 32 KB
    unsigned short* parth = (unsigned short*)(ws + (13u << 20));          // 8 x 2 MB (fp16)
    (void)ws_size;

    float* f1f2_l[3] = { f1f2, f1f2 + 8192, f1f2 + 16384 };

    // union setup (LDS-free, ballot-free adj): adj (4096) ∥ W1-3 cvt (768) ∥ zero (96) ∥ proj0 (512)
    setup_p0<<<5472, 256, 0, stream>>>(input, adj, W0, W1, W2, W3, bits, h1, Wbt, f1f2);

    // layer 1
    proj_gemm<<<512, 256, 0, stream>>>(h1, Wbt + 1 * 65536, a1, f1f2_l[0], Whbt);
    rowcoef<<<512, 256, 0, stream>>>(bits, f1f2_l[0], rowco, tab2);
    att_gemm<16><<<512, 256, 0, stream>>>(bits, rowco, (const float*)tab2, Whbt, parth);

    // layer 2
    fused_rp<8><<<256, 256, 0, stream>>>(parth, Wbt + 2 * 65536, a2, f1f2_l[1], Whbt);
    rowcoef<<<512, 256, 0, stream>>>(bits, f1f2_l[1], rowco, tab2);
    att_gemm<16><<<512, 256, 0, stream>>>(bits, rowco, (const float*)tab2, Whbt, parth);

    // layer 3
    fused_rp<8><<<256, 256, 0, stream>>>(parth, Wbt + 3 * 65536, a3, f1f2_l[2], Whbt);
    rowcoef<<<512, 256, 0, stream>>>(bits, f1f2_l[2], rowco, tab2);
    att_gemm<16><<<512, 256, 0, stream>>>(bits, rowco, (const float*)tab2, Whbt, parth);
    reduce_out<8><<<512, 256, 0, stream>>>(parth, out);
}